// Round 3
// baseline (656.639 us; speedup 1.0000x reference)
//
#include <hip/hip_runtime.h>

#define BB 8
#define NNODES 1024
#define FIN 64
#define NH 4
#define NC 32
#define HDIM 128          // HIN == HID == 128
#define NEG_INF_F (-1e9f)

#define LOGITS_CNT (BB*NNODES*NNODES*3)   // 25165824
#define HP_OFF LOGITS_CNT

// workspace layout (float offsets)
#define WS_HH    0
#define WS_SSRC  (WS_HH    + BB*NNODES*HDIM)   // [B][N][4]
#define WS_SDSTT (WS_SSRC  + BB*NNODES*NH)     // [B][4][N]
#define WS_M     (WS_SDSTT + BB*NH*NNODES)     // [B][N][4]
#define WS_RSUM  (WS_M     + BB*NNODES*NH)     // [B][N][4]
#define WS_CONV  (WS_RSUM  + BB*NNODES*NH)     // [B][N][128]
#define WS_T     (WS_CONV  + BB*NNODES*HDIM)   // [B][3][N][128]

__device__ __forceinline__ float sigmoidf_(float x) { return 1.0f/(1.0f+__expf(-x)); }
__device__ __forceinline__ float tanhf_(float x) {
  float e = __expf(2.0f*x); return 1.0f - 2.0f/(e+1.0f);
}
__device__ __forceinline__ void ld4(const float* p, float* d) {
  float4 v = *(const float4*)p;
  d[0]=v.x; d[1]=v.y; d[2]=v.z; d[3]=v.w;
}

// ---------------- Kernel A: hh = x@Wk, per-node src/dst scores ----------------
__global__ __launch_bounds__(256) void k_hh_scores(
    const float* __restrict__ x, const float* __restrict__ Wk,
    const float* __restrict__ att_src, const float* __restrict__ att_dst,
    float* __restrict__ ws)
{
  __shared__ float wk_l[FIN*HDIM];   // 64x128 = 32KB
  __shared__ float x_l[8][FIN];      // 2KB
  int tid = threadIdx.x;
  int blk = blockIdx.x;
  int b = blk >> 7;                  // 128 blocks per batch
  int n0 = (blk & 127) * 8;
  #pragma unroll
  for (int t = 0; t < 8; ++t) {
    int idx = tid + t*256;           // float4 index over 2048
    int r = idx >> 5, c4 = idx & 31;
    *(float4*)&wk_l[r*HDIM + c4*4] = *(const float4*)&Wk[r*HDIM + c4*4];
  }
  if (tid < 128) {
    int r = tid >> 4, c4 = tid & 15;
    *(float4*)&x_l[r][c4*4] = *(const float4*)&x[((size_t)(b*NNODES)+n0+r)*FIN + c4*4];
  }
  __syncthreads();
  int col = tid & 127;
  int rh = tid >> 7;
  float as = att_src[col], ad = att_dst[col];
  float acc[4];
  #pragma unroll
  for (int rr = 0; rr < 4; ++rr) acc[rr] = 0.f;
  for (int k = 0; k < FIN; ++k) {
    float wv = wk_l[k*HDIM + col];
    #pragma unroll
    for (int rr = 0; rr < 4; ++rr)
      acc[rr] = fmaf(x_l[rh*4+rr][k], wv, acc[rr]);
  }
  float* hh    = ws + WS_HH;
  float* ssrc  = ws + WS_SSRC;
  float* sdstT = ws + WS_SDSTT;
  int hI = col >> 5;
  #pragma unroll
  for (int rr = 0; rr < 4; ++rr) {
    int n = n0 + rh*4 + rr;
    hh[((size_t)(b*NNODES)+n)*HDIM + col] = acc[rr];
    float ss = acc[rr]*as, sd = acc[rr]*ad;
    #pragma unroll
    for (int m = 16; m >= 1; m >>= 1) {
      ss += __shfl_xor(ss, m, 64);
      sd += __shfl_xor(sd, m, 64);
    }
    if ((col & 31) == 0) {
      ssrc[((size_t)(b*NNODES)+n)*NH + hI] = ss;
      sdstT[(size_t)(b*NH + hI)*NNODES + n] = sd;
    }
  }
}

// ---------------- Kernel B: softmax stats (max, 1/sum) per (b,i,h) ----------------
__global__ __launch_bounds__(256) void k_stats(
    const float* __restrict__ a, float* __restrict__ ws)
{
  __shared__ float a_l[NNODES];  // 4KB
  int tid = threadIdx.x;
  int blk = blockIdx.x;
  int b = blk >> 10, i = blk & 1023;
  const float* arow = a + ((size_t)(b*NNODES + i))*NNODES;
  *(float4*)&a_l[tid*4] = *(const float4*)&arow[tid*4];
  __syncthreads();
  int h = tid >> 6, lane = tid & 63;
  const float* ssrc  = ws + WS_SSRC;
  const float* sdstT = ws + WS_SDSTT;
  float si = ssrc[((size_t)(b*NNODES)+i)*NH + h];
  float e[16];
  float mx = -3.4e38f;
  #pragma unroll
  for (int t = 0; t < 16; ++t) {
    int j = lane + t*64;
    float s = si + sdstT[(size_t)(b*NH+h)*NNODES + j];
    float ev = s >= 0.f ? s : 0.2f*s;
    ev += NEG_INF_F * (1.0f - a_l[j]);
    e[t] = ev;
    mx = fmaxf(mx, ev);
  }
  #pragma unroll
  for (int m = 32; m >= 1; m >>= 1) mx = fmaxf(mx, __shfl_xor(mx, m, 64));
  float sum = 0.f;
  #pragma unroll
  for (int t = 0; t < 16; ++t) sum += __expf(e[t] - mx);
  #pragma unroll
  for (int m = 32; m >= 1; m >>= 1) sum += __shfl_xor(sum, m, 64);
  if (lane == 0) {
    ws[WS_M    + ((size_t)(b*NNODES)+i)*NH + h] = mx;
    ws[WS_RSUM + ((size_t)(b*NNODES)+i)*NH + h] = 1.0f / sum;
  }
}

// ---------------- Kernel C: conv = softmax(e) @ hh, + bias (BM=16, 2 blk/CU) ----
#define CBM 16
#define P_HS 66
#define P_RS 268
__global__ __launch_bounds__(256) void k_conv(
    const float* __restrict__ a, const float* __restrict__ bias_gat,
    float* __restrict__ ws)
{
  __shared__ float hh_l[64*HDIM];      // 32KB
  __shared__ float p_l[CBM][P_RS];     // 17.2KB
  __shared__ float aT[CBM][64];        // 4KB
  __shared__ float ssrc_l[CBM][4], m_l[CBM][4], rs_l[CBM][4];
  int tid = threadIdx.x;
  int blk = blockIdx.x;
  int b = blk >> 6;
  int i0 = (blk & 63) * CBM;
  const float* hh    = ws + WS_HH;
  const float* sdstT = ws + WS_SDSTT;
  if (tid < 64) {
    int r = tid >> 2, h = tid & 3;
    ssrc_l[r][h] = ws[WS_SSRC + ((size_t)(b*NNODES)+i0+r)*NH + h];
    m_l[r][h]    = ws[WS_M    + ((size_t)(b*NNODES)+i0+r)*NH + h];
    rs_l[r][h]   = ws[WS_RSUM + ((size_t)(b*NNODES)+i0+r)*NH + h];
  }
  int jj = tid & 63, hF = tid >> 6;          // phase-1 mapping
  int col4 = tid & 31, rg = tid >> 5;        // phase-2 mapping (rg 0..7)
  int h2 = col4 >> 3;
  float acc[2][4];
  #pragma unroll
  for (int r = 0; r < 2; ++r)
    #pragma unroll
    for (int c = 0; c < 4; ++c) acc[r][c] = 0.f;
  __syncthreads();
  for (int jt = 0; jt < 16; ++jt) {
    int j0 = jt * 64;
    #pragma unroll
    for (int t = 0; t < 8; ++t) {            // hh chunk [64][128]
      int idx = tid + t*256;
      int r = idx >> 5, c4 = idx & 31;
      *(float4*)&hh_l[r*HDIM + c4*4] =
        *(const float4*)&hh[((size_t)(b*NNODES) + j0 + r)*HDIM + c4*4];
    }
    {                                         // a tile [16][64]
      int r = tid >> 4, jq = tid & 15;
      *(float4*)&aT[r][jq*4] =
        *(const float4*)&a[((size_t)(b*NNODES) + i0 + r)*NNODES + j0 + jq*4];
    }
    float sd = sdstT[(size_t)(b*NH + hF)*NNODES + j0 + jj];
    __syncthreads();
    // phase 1: p = softmax prob for (row, hF, jj)
    #pragma unroll 4
    for (int r = 0; r < CBM; ++r) {
      float s = ssrc_l[r][hF] + sd;
      float ev = s >= 0.f ? s : 0.2f*s;
      ev += NEG_INF_F*(1.0f - aT[r][jj]);
      p_l[r][hF*P_HS + jj] = __expf(ev - m_l[r][hF]) * rs_l[r][hF];
    }
    __syncthreads();
    // phase 2: acc += p * hh
    for (int j = 0; j < 64; ++j) {
      float hv[4];
      ld4(&hh_l[j*HDIM + col4*4], hv);
      #pragma unroll
      for (int rr = 0; rr < 2; ++rr) {
        float pv = p_l[rg*2+rr][h2*P_HS + j];
        #pragma unroll
        for (int c = 0; c < 4; ++c)
          acc[rr][c] = fmaf(pv, hv[c], acc[rr][c]);
      }
    }
    __syncthreads();
  }
  float bias[4];
  ld4(&bias_gat[col4*4], bias);
  float* conv = ws + WS_CONV;
  #pragma unroll
  for (int rr = 0; rr < 2; ++rr) {
    int n = i0 + rg*2 + rr;
    float4 o;
    o.x = acc[rr][0] + bias[0]; o.y = acc[rr][1] + bias[1];
    o.z = acc[rr][2] + bias[2]; o.w = acc[rr][3] + bias[3];
    *(float4*)&conv[((size_t)(b*NNODES) + n)*HDIM + col4*4] = o;
  }
}

// ---------------- Kernel D: GRU-style gated update (LDS-staged GEMM) ----------
#define GBM 16
__global__ __launch_bounds__(256) void k_gru2(
    const float* __restrict__ h_in,
    const float* __restrict__ b_u, const float* __restrict__ b_r, const float* __restrict__ b_c,
    const float* __restrict__ W_u, const float* __restrict__ W_r, const float* __restrict__ W_c,
    float* __restrict__ ws, float* __restrict__ out)
{
  __shared__ float cu_l[GBM][260];   // 16.6KB  [row][k]: k<128 conv, k>=128 h
  __shared__ float w_l[64][132];     // 33.8KB  one 64-k chunk of one gate
  __shared__ float rh_l[GBM][132];   // 8.4KB
  int tid = threadIdx.x;
  int blk = blockIdx.x;
  int b = blk >> 6;
  int n0 = (blk & 63) * GBM;
  const float* conv = ws + WS_CONV;
  #pragma unroll
  for (int t = 0; t < 4; ++t) {
    int idx = tid + t*256;           // float4 over 1024 slots
    int r = idx >> 6, c4 = idx & 63;
    float4 v;
    if (c4 < 32) v = *(const float4*)&conv[((size_t)(b*NNODES)+n0+r)*HDIM + c4*4];
    else         v = *(const float4*)&h_in[((size_t)(b*NNODES)+n0+r)*HDIM + (c4-32)*4];
    *(float4*)&cu_l[r][c4*4] = v;
  }
  int cg = tid & 31, rgp = tid >> 5;   // cols cg*4..+3, rows rgp*2..+1
  int col0 = cg*4;
  int row0 = rgp*2;

#define LOAD_W(Wg, chunk) do {                                              \
    __syncthreads();                                                        \
    _Pragma("unroll")                                                       \
    for (int t_ = 0; t_ < 8; ++t_) {                                        \
      int idx_ = tid + t_*256;                                              \
      int r_ = idx_ >> 5, c4_ = idx_ & 31;                                  \
      *(float4*)&w_l[r_][c4_*4] =                                           \
        *(const float4*)&Wg[(size_t)((chunk)*64 + r_)*HDIM + c4_*4];        \
    }                                                                       \
    __syncthreads();                                                        \
  } while(0)

#define ACC_K(acc, A0EXPR, A1EXPR) do {                                     \
    for (int k_ = 0; k_ < 64; ++k_) {                                       \
      float4 wv = *(const float4*)&w_l[k_][col0];                           \
      float a0_ = (A0EXPR), a1_ = (A1EXPR);                                 \
      acc[0][0]=fmaf(a0_,wv.x,acc[0][0]); acc[0][1]=fmaf(a0_,wv.y,acc[0][1]);\
      acc[0][2]=fmaf(a0_,wv.z,acc[0][2]); acc[0][3]=fmaf(a0_,wv.w,acc[0][3]);\
      acc[1][0]=fmaf(a1_,wv.x,acc[1][0]); acc[1][1]=fmaf(a1_,wv.y,acc[1][1]);\
      acc[1][2]=fmaf(a1_,wv.z,acc[1][2]); acc[1][3]=fmaf(a1_,wv.w,acc[1][3]);\
    }                                                                       \
  } while(0)

  float accU[2][4], accR[2][4], accC[2][4];
  #pragma unroll
  for (int r = 0; r < 2; ++r)
    #pragma unroll
    for (int c = 0; c < 4; ++c) { accU[r][c]=0.f; accR[r][c]=0.f; accC[r][c]=0.f; }

  for (int ch = 0; ch < 4; ++ch) {
    LOAD_W(W_u, ch);
    ACC_K(accU, cu_l[row0][ch*64+k_], cu_l[row0+1][ch*64+k_]);
  }
  for (int ch = 0; ch < 4; ++ch) {
    LOAD_W(W_r, ch);
    ACC_K(accR, cu_l[row0][ch*64+k_], cu_l[row0+1][ch*64+k_]);
  }
  // u, r; rh = r*h
  float uu[2][4];
  #pragma unroll
  for (int rr = 0; rr < 2; ++rr) {
    float bu_ = b_u[n0 + row0 + rr];
    float br_ = b_r[n0 + row0 + rr];
    float4 rv;
    uu[rr][0] = sigmoidf_(bu_ + accU[rr][0]);
    uu[rr][1] = sigmoidf_(bu_ + accU[rr][1]);
    uu[rr][2] = sigmoidf_(bu_ + accU[rr][2]);
    uu[rr][3] = sigmoidf_(bu_ + accU[rr][3]);
    rv.x = sigmoidf_(br_ + accR[rr][0]) * cu_l[row0+rr][128+col0+0];
    rv.y = sigmoidf_(br_ + accR[rr][1]) * cu_l[row0+rr][128+col0+1];
    rv.z = sigmoidf_(br_ + accR[rr][2]) * cu_l[row0+rr][128+col0+2];
    rv.w = sigmoidf_(br_ + accR[rr][3]) * cu_l[row0+rr][128+col0+3];
    *(float4*)&rh_l[row0+rr][col0] = rv;
  }
  // C gate: k 0..127 from conv part of cu_l, k 128..255 from rh_l
  for (int ch = 0; ch < 2; ++ch) {
    LOAD_W(W_c, ch);
    ACC_K(accC, cu_l[row0][ch*64+k_], cu_l[row0+1][ch*64+k_]);
  }
  for (int ch = 2; ch < 4; ++ch) {
    LOAD_W(W_c, ch);
    ACC_K(accC, rh_l[row0][(ch-2)*64+k_], rh_l[row0+1][(ch-2)*64+k_]);
  }
  #pragma unroll
  for (int rr = 0; rr < 2; ++rr) {
    float bc_ = b_c[n0 + row0 + rr];
    float4 o;
    float hv0 = cu_l[row0+rr][128+col0+0];
    float hv1 = cu_l[row0+rr][128+col0+1];
    float hv2 = cu_l[row0+rr][128+col0+2];
    float hv3 = cu_l[row0+rr][128+col0+3];
    float c0 = tanhf_(bc_ + accC[rr][0]);
    float c1 = tanhf_(bc_ + accC[rr][1]);
    float c2 = tanhf_(bc_ + accC[rr][2]);
    float c3 = tanhf_(bc_ + accC[rr][3]);
    o.x = uu[rr][0]*hv0 + (1.0f-uu[rr][0])*c0;
    o.y = uu[rr][1]*hv1 + (1.0f-uu[rr][1])*c1;
    o.z = uu[rr][2]*hv2 + (1.0f-uu[rr][2])*c2;
    o.w = uu[rr][3]*hv3 + (1.0f-uu[rr][3])*c3;
    *(float4*)&out[HP_OFF + ((size_t)(b*NNODES)+n0+row0+rr)*HDIM + col0] = o;
  }
#undef LOAD_W
#undef ACC_K
}

// ---------------- Kernel E: T[b][k3] = h' @ R_k3 ----------------
#define HP_S 132
__global__ __launch_bounds__(128) void k_T(
    const float* __restrict__ R_p, const float* __restrict__ R_mu, const float* __restrict__ R_sg,
    const float* __restrict__ out, float* __restrict__ ws)
{
  __shared__ float hp_l[32*HP_S];  // 16.9KB
  int tid = threadIdx.x;
  int blk = blockIdx.x;
  int b = blk / 96;
  int rem = blk % 96;
  int k3 = rem >> 5;
  int n0 = (rem & 31) * 32;
  const float* hp = out + HP_OFF;
  const float* R = (k3 == 0) ? R_p : (k3 == 1) ? R_mu : R_sg;
  #pragma unroll
  for (int t = 0; t < 8; ++t) {
    int idx = tid + t*128;          // float4 over 1024
    int r = idx >> 5, c4 = idx & 31;
    *(float4*)&hp_l[r*HP_S + c4*4] =
      *(const float4*)&hp[((size_t)(b*NNODES)+n0+r)*HDIM + c4*4];
  }
  __syncthreads();
  int cg = tid & 31, rg = tid >> 5;   // cols cg*4..+3, rows rg + 4*rr
  float acc[8][4];
  #pragma unroll
  for (int rr = 0; rr < 8; ++rr)
    #pragma unroll
    for (int c = 0; c < 4; ++c) acc[rr][c] = 0.f;
  for (int k4 = 0; k4 < 32; ++k4) {
    float w[4][4];
    #pragma unroll
    for (int kk = 0; kk < 4; ++kk) ld4(&R[(size_t)(k4*4+kk)*HDIM + cg*4], w[kk]);
    #pragma unroll
    for (int rr = 0; rr < 8; ++rr) {
      float hv[4];
      ld4(&hp_l[(rg + 4*rr)*HP_S + k4*4], hv);
      #pragma unroll
      for (int c = 0; c < 4; ++c) {
        float s = acc[rr][c];
        s = fmaf(hv[0], w[0][c], s);
        s = fmaf(hv[1], w[1][c], s);
        s = fmaf(hv[2], w[2][c], s);
        s = fmaf(hv[3], w[3][c], s);
        acc[rr][c] = s;
      }
    }
  }
  float* T = ws + WS_T;
  #pragma unroll
  for (int rr = 0; rr < 8; ++rr) {
    int row = rg + 4*rr;
    float4 o; o.x=acc[rr][0]; o.y=acc[rr][1]; o.z=acc[rr][2]; o.w=acc[rr][3];
    *(float4*)&T[((size_t)((b*3+k3)*NNODES)+n0+row)*HDIM + cg*4] = o;
  }
}

// ---------------- Kernel F: logits[b,n,m,0..2] fused over 3 decoders ----------
#define FT_S 132
__global__ __launch_bounds__(256) void k_logits(
    const float* __restrict__ ws, const float* __restrict__ out_hp, float* __restrict__ out)
{
  __shared__ float t_l[64*FT_S];    // 33.8KB
  __shared__ float hp_l[64*FT_S];   // 33.8KB
  int tid = threadIdx.x;
  int blk = blockIdx.x;
  int b = blk >> 8;
  int nt = (blk >> 4) & 15, mt = blk & 15;
  int n0 = nt*64, m0 = mt*64;
  const float* hp = out_hp + HP_OFF;
  const float* T = ws + WS_T;
  #pragma unroll
  for (int t = 0; t < 8; ++t) {
    int idx = tid + t*256;
    int r = idx >> 5, c4 = idx & 31;
    *(float4*)&hp_l[r*FT_S + c4*4] =
      *(const float4*)&hp[((size_t)(b*NNODES)+m0+r)*HDIM + c4*4];
  }
  int ng = tid >> 4, mg = tid & 15;
  float lg[3][4][4];
  for (int k3 = 0; k3 < 3; ++k3) {
    __syncthreads();
    #pragma unroll
    for (int t = 0; t < 8; ++t) {
      int idx = tid + t*256;
      int r = idx >> 5, c4 = idx & 31;
      *(float4*)&t_l[r*FT_S + c4*4] =
        *(const float4*)&T[((size_t)((b*3+k3)*NNODES)+n0+r)*HDIM + c4*4];
    }
    __syncthreads();
    float acc[4][4];
    #pragma unroll
    for (int nn = 0; nn < 4; ++nn)
      #pragma unroll
      for (int mm = 0; mm < 4; ++mm) acc[nn][mm] = 0.f;
    for (int k4 = 0; k4 < 32; ++k4) {
      float tv[4][4], hv[4][4];
      #pragma unroll
      for (int nn = 0; nn < 4; ++nn) ld4(&t_l[(ng*4+nn)*FT_S + k4*4], tv[nn]);
      #pragma unroll
      for (int mm = 0; mm < 4; ++mm) ld4(&hp_l[(mg+16*mm)*FT_S + k4*4], hv[mm]);
      #pragma unroll
      for (int nn = 0; nn < 4; ++nn)
        #pragma unroll
        for (int mm = 0; mm < 4; ++mm) {
          float s = acc[nn][mm];
          s = fmaf(tv[nn][0], hv[mm][0], s);
          s = fmaf(tv[nn][1], hv[mm][1], s);
          s = fmaf(tv[nn][2], hv[mm][2], s);
          s = fmaf(tv[nn][3], hv[mm][3], s);
          acc[nn][mm] = s;
        }
    }
    #pragma unroll
    for (int nn = 0; nn < 4; ++nn)
      #pragma unroll
      for (int mm = 0; mm < 4; ++mm) lg[k3][nn][mm] = acc[nn][mm];
  }
  #pragma unroll
  for (int nn = 0; nn < 4; ++nn) {
    size_t base = ((size_t)(b*NNODES) + n0 + ng*4 + nn)*NNODES;
    #pragma unroll
    for (int mm = 0; mm < 4; ++mm) {
      size_t m = m0 + mg + 16*mm;
      float* po = &out[(base + m)*3];
      po[0] = lg[0][nn][mm];
      po[1] = lg[1][nn][mm];
      po[2] = lg[2][nn][mm];
    }
  }
}

extern "C" void kernel_launch(void* const* d_in, const int* in_sizes, int n_in,
                              void* d_out, int out_size, void* d_ws, size_t ws_size,
                              hipStream_t stream) {
  (void)in_sizes; (void)n_in; (void)out_size; (void)ws_size;
  const float* x        = (const float*)d_in[0];
  const float* a        = (const float*)d_in[1];
  const float* h        = (const float*)d_in[2];
  const float* Wk       = (const float*)d_in[3];
  const float* att_src  = (const float*)d_in[4];
  const float* att_dst  = (const float*)d_in[5];
  const float* bias_gat = (const float*)d_in[6];
  const float* b_u      = (const float*)d_in[7];
  const float* b_r      = (const float*)d_in[8];
  const float* b_c      = (const float*)d_in[9];
  const float* W_u      = (const float*)d_in[10];
  const float* W_r      = (const float*)d_in[11];
  const float* W_c      = (const float*)d_in[12];
  const float* R_p      = (const float*)d_in[13];
  const float* R_mu     = (const float*)d_in[14];
  const float* R_sg     = (const float*)d_in[15];
  float* out = (float*)d_out;
  float* ws  = (float*)d_ws;

  hipLaunchKernelGGL(k_hh_scores, dim3(1024), dim3(256), 0, stream,
                     x, Wk, att_src, att_dst, ws);
  hipLaunchKernelGGL(k_stats, dim3(8192), dim3(256), 0, stream, a, ws);
  hipLaunchKernelGGL(k_conv, dim3(512), dim3(256), 0, stream, a, bias_gat, ws);
  hipLaunchKernelGGL(k_gru2, dim3(512), dim3(256), 0, stream,
                     h, b_u, b_r, b_c, W_u, W_r, W_c, ws, out);
  hipLaunchKernelGGL(k_T, dim3(768), dim3(128), 0, stream, R_p, R_mu, R_sg, out, ws);
  hipLaunchKernelGGL(k_logits, dim3(2048), dim3(256), 0, stream, ws, out, out);
}

// Round 4
// 251.415 us; speedup vs baseline: 2.6118x; 2.6118x over previous
//
#include <hip/hip_runtime.h>

#define BB 8
#define NNODES 1024
#define FIN 64
#define NH 4
#define NC 32
#define HDIM 128          // HIN == HID == 128
#define NEG_INF_F (-1e9f)

#define LOGITS_CNT (BB*NNODES*NNODES*3)   // 25165824
#define HP_OFF LOGITS_CNT

// scratch inside the (not-yet-written) logits region of d_out
#define U_OFF  0                      // u  [B*N][128]
#define RH_OFF (BB*NNODES*HDIM)       // rh [B*N][128]

// workspace layout (float offsets)
#define WS_HH    0
#define WS_SSRC  (WS_HH    + BB*NNODES*HDIM)   // [B][N][4]
#define WS_SDSTT (WS_SSRC  + BB*NNODES*NH)     // [B][4][N]
#define WS_M     (WS_SDSTT + BB*NH*NNODES)     // [B][N][4]
#define WS_RSUM  (WS_M     + BB*NNODES*NH)     // [B][N][4]
#define WS_CONV  (WS_RSUM  + BB*NNODES*NH)     // [B][N][128]
#define WS_T     (WS_CONV  + BB*NNODES*HDIM)   // [B][3][N][128]

__device__ __forceinline__ float sigmoidf_(float x) { return 1.0f/(1.0f+__expf(-x)); }
__device__ __forceinline__ float tanhf_(float x) {
  float e = __expf(2.0f*x); return 1.0f - 2.0f/(e+1.0f);
}
__device__ __forceinline__ void ld4(const float* p, float* d) {
  float4 v = *(const float4*)p;
  d[0]=v.x; d[1]=v.y; d[2]=v.z; d[3]=v.w;
}

// ---------------- Kernel A: hh = x@Wk, per-node src/dst scores ----------------
__global__ __launch_bounds__(256) void k_hh_scores(
    const float* __restrict__ x, const float* __restrict__ Wk,
    const float* __restrict__ att_src, const float* __restrict__ att_dst,
    float* __restrict__ ws)
{
  __shared__ float wk_l[FIN*HDIM];   // 64x128 = 32KB
  __shared__ float x_l[8][FIN];      // 2KB
  int tid = threadIdx.x;
  int blk = blockIdx.x;
  int b = blk >> 7;                  // 128 blocks per batch
  int n0 = (blk & 127) * 8;
  #pragma unroll
  for (int t = 0; t < 8; ++t) {
    int idx = tid + t*256;           // float4 index over 2048
    int r = idx >> 5, c4 = idx & 31;
    *(float4*)&wk_l[r*HDIM + c4*4] = *(const float4*)&Wk[r*HDIM + c4*4];
  }
  if (tid < 128) {
    int r = tid >> 4, c4 = tid & 15;
    *(float4*)&x_l[r][c4*4] = *(const float4*)&x[((size_t)(b*NNODES)+n0+r)*FIN + c4*4];
  }
  __syncthreads();
  int col = tid & 127;
  int rh = tid >> 7;
  float as = att_src[col], ad = att_dst[col];
  float acc[4];
  #pragma unroll
  for (int rr = 0; rr < 4; ++rr) acc[rr] = 0.f;
  for (int k = 0; k < FIN; ++k) {
    float wv = wk_l[k*HDIM + col];
    #pragma unroll
    for (int rr = 0; rr < 4; ++rr)
      acc[rr] = fmaf(x_l[rh*4+rr][k], wv, acc[rr]);
  }
  float* hh    = ws + WS_HH;
  float* ssrc  = ws + WS_SSRC;
  float* sdstT = ws + WS_SDSTT;
  int hI = col >> 5;
  #pragma unroll
  for (int rr = 0; rr < 4; ++rr) {
    int n = n0 + rh*4 + rr;
    hh[((size_t)(b*NNODES)+n)*HDIM + col] = acc[rr];
    float ss = acc[rr]*as, sd = acc[rr]*ad;
    #pragma unroll
    for (int m = 16; m >= 1; m >>= 1) {
      ss += __shfl_xor(ss, m, 64);
      sd += __shfl_xor(sd, m, 64);
    }
    if ((col & 31) == 0) {
      ssrc[((size_t)(b*NNODES)+n)*NH + hI] = ss;
      sdstT[(size_t)(b*NH + hI)*NNODES + n] = sd;
    }
  }
}

// ---------------- Kernel B: softmax stats (max, 1/sum) per (b,i,h) ----------------
__global__ __launch_bounds__(256) void k_stats(
    const float* __restrict__ a, float* __restrict__ ws)
{
  __shared__ float a_l[NNODES];  // 4KB
  int tid = threadIdx.x;
  int blk = blockIdx.x;
  int b = blk & 7, i = blk >> 3;     // b-major on XCD
  const float* arow = a + ((size_t)(b*NNODES + i))*NNODES;
  *(float4*)&a_l[tid*4] = *(const float4*)&arow[tid*4];
  __syncthreads();
  int h = tid >> 6, lane = tid & 63;
  const float* ssrc  = ws + WS_SSRC;
  const float* sdstT = ws + WS_SDSTT;
  float si = ssrc[((size_t)(b*NNODES)+i)*NH + h];
  float e[16];
  float mx = -3.4e38f;
  #pragma unroll
  for (int t = 0; t < 16; ++t) {
    int j = lane + t*64;
    float s = si + sdstT[(size_t)(b*NH+h)*NNODES + j];
    float ev = s >= 0.f ? s : 0.2f*s;
    ev += NEG_INF_F * (1.0f - a_l[j]);
    e[t] = ev;
    mx = fmaxf(mx, ev);
  }
  #pragma unroll
  for (int m = 32; m >= 1; m >>= 1) mx = fmaxf(mx, __shfl_xor(mx, m, 64));
  float sum = 0.f;
  #pragma unroll
  for (int t = 0; t < 16; ++t) sum += __expf(e[t] - mx);
  #pragma unroll
  for (int m = 32; m >= 1; m >>= 1) sum += __shfl_xor(sum, m, 64);
  if (lane == 0) {
    ws[WS_M    + ((size_t)(b*NNODES)+i)*NH + h] = mx;
    ws[WS_RSUM + ((size_t)(b*NNODES)+i)*NH + h] = 1.0f / sum;
  }
}

// ---------------- Kernel C: conv = softmax(e) @ hh, + bias ----------------
#define CBM 16
#define P_HS 66
#define P_RS 268
__global__ __launch_bounds__(256) void k_conv(
    const float* __restrict__ a, const float* __restrict__ bias_gat,
    float* __restrict__ ws)
{
  __shared__ float hh_l[64*HDIM];      // 32KB
  __shared__ float p_l[CBM][P_RS];     // 17.2KB
  __shared__ float aT[CBM][64];        // 4KB
  __shared__ float ssrc_l[CBM][4], m_l[CBM][4], rs_l[CBM][4];
  int tid = threadIdx.x;
  int blk = blockIdx.x;
  int b = blk & 7;                     // XCD-local batch
  int i0 = (blk >> 3) * CBM;
  const float* hh    = ws + WS_HH;
  const float* sdstT = ws + WS_SDSTT;
  if (tid < 64) {
    int r = tid >> 2, h = tid & 3;
    ssrc_l[r][h] = ws[WS_SSRC + ((size_t)(b*NNODES)+i0+r)*NH + h];
    m_l[r][h]    = ws[WS_M    + ((size_t)(b*NNODES)+i0+r)*NH + h];
    rs_l[r][h]   = ws[WS_RSUM + ((size_t)(b*NNODES)+i0+r)*NH + h];
  }
  int jj = tid & 63, hF = tid >> 6;          // phase-1 mapping
  int col4 = tid & 31, rg = tid >> 5;        // phase-2 mapping (rg 0..7)
  int h2 = col4 >> 3;
  float acc[2][4];
  #pragma unroll
  for (int r = 0; r < 2; ++r)
    #pragma unroll
    for (int c = 0; c < 4; ++c) acc[r][c] = 0.f;
  __syncthreads();
  for (int jt = 0; jt < 16; ++jt) {
    int j0 = jt * 64;
    #pragma unroll
    for (int t = 0; t < 8; ++t) {            // hh chunk [64][128]
      int idx = tid + t*256;
      int r = idx >> 5, c4 = idx & 31;
      *(float4*)&hh_l[r*HDIM + c4*4] =
        *(const float4*)&hh[((size_t)(b*NNODES) + j0 + r)*HDIM + c4*4];
    }
    {                                         // a tile [16][64]
      int r = tid >> 4, jq = tid & 15;
      *(float4*)&aT[r][jq*4] =
        *(const float4*)&a[((size_t)(b*NNODES) + i0 + r)*NNODES + j0 + jq*4];
    }
    float sd = sdstT[(size_t)(b*NH + hF)*NNODES + j0 + jj];
    __syncthreads();
    // phase 1: p = softmax prob for (row, hF, jj)
    #pragma unroll 4
    for (int r = 0; r < CBM; ++r) {
      float s = ssrc_l[r][hF] + sd;
      float ev = s >= 0.f ? s : 0.2f*s;
      ev += NEG_INF_F*(1.0f - aT[r][jj]);
      p_l[r][hF*P_HS + jj] = __expf(ev - m_l[r][hF]) * rs_l[r][hF];
    }
    __syncthreads();
    // phase 2: acc += p * hh
    for (int j = 0; j < 64; ++j) {
      float hv[4];
      ld4(&hh_l[j*HDIM + col4*4], hv);
      #pragma unroll
      for (int rr = 0; rr < 2; ++rr) {
        float pv = p_l[rg*2+rr][h2*P_HS + j];
        #pragma unroll
        for (int c = 0; c < 4; ++c)
          acc[rr][c] = fmaf(pv, hv[c], acc[rr][c]);
      }
    }
    __syncthreads();
  }
  float bias[4];
  ld4(&bias_gat[col4*4], bias);
  float* conv = ws + WS_CONV;
  #pragma unroll
  for (int rr = 0; rr < 2; ++rr) {
    int n = i0 + rg*2 + rr;
    float4 o;
    o.x = acc[rr][0] + bias[0]; o.y = acc[rr][1] + bias[1];
    o.z = acc[rr][2] + bias[2]; o.w = acc[rr][3] + bias[3];
    *(float4*)&conv[((size_t)(b*NNODES) + n)*HDIM + col4*4] = o;
  }
}

// ---------------- Kernel D1: u and r*h via tiled GEMM (BM64 BN64 BK32) -------
// grid 512: blk = mtile*4 + ntile*2 + gate
__global__ __launch_bounds__(256) void k_gruA(
    const float* __restrict__ h_in,
    const float* __restrict__ b_u, const float* __restrict__ b_r,
    const float* __restrict__ W_u, const float* __restrict__ W_r,
    const float* __restrict__ ws, float* __restrict__ out)
{
  __shared__ float a_l[64][36];   // 9.2KB (pad 36: 2-way max on act reads)
  __shared__ float w_l[32][64];   // 8KB
  int tid = threadIdx.x;
  int blk = blockIdx.x;
  int g = blk & 1;
  int ntile = (blk >> 1) & 1;
  int mbase = (blk >> 2) * 64;
  const float* conv = ws + WS_CONV;
  const float* Wg = g ? W_r : W_u;
  int ncol0 = ntile * 64;
  int rg = tid >> 4, cg = tid & 15;
  int col0 = cg * 4;
  float acc[4][4] = {{0.f}};
  for (int kc = 0; kc < 8; ++kc) {
    const float* abase = (kc < 4) ? conv : h_in;
    int coff = (kc & 3) * 32;
    __syncthreads();
    #pragma unroll
    for (int t = 0; t < 2; ++t) {
      int idx = tid + t*256;
      int r = idx >> 3, q = idx & 7;
      *(float4*)&a_l[r][q*4] =
        *(const float4*)&abase[(size_t)(mbase + r)*HDIM + coff + q*4];
    }
    #pragma unroll
    for (int t = 0; t < 2; ++t) {
      int idx = tid + t*256;
      int r = idx >> 4, q = idx & 15;
      *(float4*)&w_l[r][q*4] =
        *(const float4*)&Wg[(size_t)(kc*32 + r)*HDIM + ncol0 + q*4];
    }
    __syncthreads();
    for (int k = 0; k < 32; ++k) {
      float4 wv = *(const float4*)&w_l[k][col0];
      #pragma unroll
      for (int rr = 0; rr < 4; ++rr) {
        float av = a_l[rg*4+rr][k];
        acc[rr][0] = fmaf(av, wv.x, acc[rr][0]);
        acc[rr][1] = fmaf(av, wv.y, acc[rr][1]);
        acc[rr][2] = fmaf(av, wv.z, acc[rr][2]);
        acc[rr][3] = fmaf(av, wv.w, acc[rr][3]);
      }
    }
  }
  #pragma unroll
  for (int rr = 0; rr < 4; ++rr) {
    int m = mbase + rg*4 + rr;
    int n = m & (NNODES-1);
    float4 o;
    if (g == 0) {
      float bv = b_u[n];
      o.x = sigmoidf_(bv + acc[rr][0]);
      o.y = sigmoidf_(bv + acc[rr][1]);
      o.z = sigmoidf_(bv + acc[rr][2]);
      o.w = sigmoidf_(bv + acc[rr][3]);
      *(float4*)&out[U_OFF + (size_t)m*HDIM + ncol0 + col0] = o;
    } else {
      float bv = b_r[n];
      float4 hv = *(const float4*)&h_in[(size_t)m*HDIM + ncol0 + col0];
      o.x = sigmoidf_(bv + acc[rr][0]) * hv.x;
      o.y = sigmoidf_(bv + acc[rr][1]) * hv.y;
      o.z = sigmoidf_(bv + acc[rr][2]) * hv.z;
      o.w = sigmoidf_(bv + acc[rr][3]) * hv.w;
      *(float4*)&out[RH_OFF + (size_t)m*HDIM + ncol0 + col0] = o;
    }
  }
}

// ---------------- Kernel D2: c-gate GEMM + final h' ------------------------
// grid 256: blk = mtile*2 + ntile
__global__ __launch_bounds__(256) void k_gruB(
    const float* __restrict__ h_in, const float* __restrict__ b_c,
    const float* __restrict__ W_c,
    const float* __restrict__ ws, float* __restrict__ out)
{
  __shared__ float a_l[64][36];
  __shared__ float w_l[32][64];
  int tid = threadIdx.x;
  int blk = blockIdx.x;
  int ntile = blk & 1;
  int mbase = (blk >> 1) * 64;
  const float* conv = ws + WS_CONV;
  const float* rh   = out + RH_OFF;
  int ncol0 = ntile * 64;
  int rg = tid >> 4, cg = tid & 15;
  int col0 = cg * 4;
  float acc[4][4] = {{0.f}};
  for (int kc = 0; kc < 8; ++kc) {
    const float* abase = (kc < 4) ? conv : rh;
    int coff = (kc & 3) * 32;
    __syncthreads();
    #pragma unroll
    for (int t = 0; t < 2; ++t) {
      int idx = tid + t*256;
      int r = idx >> 3, q = idx & 7;
      *(float4*)&a_l[r][q*4] =
        *(const float4*)&abase[(size_t)(mbase + r)*HDIM + coff + q*4];
    }
    #pragma unroll
    for (int t = 0; t < 2; ++t) {
      int idx = tid + t*256;
      int r = idx >> 4, q = idx & 15;
      *(float4*)&w_l[r][q*4] =
        *(const float4*)&W_c[(size_t)(kc*32 + r)*HDIM + ncol0 + q*4];
    }
    __syncthreads();
    for (int k = 0; k < 32; ++k) {
      float4 wv = *(const float4*)&w_l[k][col0];
      #pragma unroll
      for (int rr = 0; rr < 4; ++rr) {
        float av = a_l[rg*4+rr][k];
        acc[rr][0] = fmaf(av, wv.x, acc[rr][0]);
        acc[rr][1] = fmaf(av, wv.y, acc[rr][1]);
        acc[rr][2] = fmaf(av, wv.z, acc[rr][2]);
        acc[rr][3] = fmaf(av, wv.w, acc[rr][3]);
      }
    }
  }
  #pragma unroll
  for (int rr = 0; rr < 4; ++rr) {
    int m = mbase + rg*4 + rr;
    int n = m & (NNODES-1);
    float bv = b_c[n];
    float4 uv = *(const float4*)&out[U_OFF + (size_t)m*HDIM + ncol0 + col0];
    float4 hv = *(const float4*)&h_in[(size_t)m*HDIM + ncol0 + col0];
    float4 o;
    o.x = uv.x*hv.x + (1.0f-uv.x)*tanhf_(bv + acc[rr][0]);
    o.y = uv.y*hv.y + (1.0f-uv.y)*tanhf_(bv + acc[rr][1]);
    o.z = uv.z*hv.z + (1.0f-uv.z)*tanhf_(bv + acc[rr][2]);
    o.w = uv.w*hv.w + (1.0f-uv.w)*tanhf_(bv + acc[rr][3]);
    *(float4*)&out[HP_OFF + (size_t)m*HDIM + ncol0 + col0] = o;
  }
}

// ---------------- Kernel E: T[b][k3] = h' @ R_k3 ----------------
#define HP_S 132
__global__ __launch_bounds__(128) void k_T(
    const float* __restrict__ R_p, const float* __restrict__ R_mu, const float* __restrict__ R_sg,
    const float* __restrict__ out, float* __restrict__ ws)
{
  __shared__ float hp_l[32*HP_S];  // 16.9KB
  int tid = threadIdx.x;
  int blk = blockIdx.x;
  int b = blk & 7;                 // XCD-local batch
  int rem = blk >> 3;              // 0..95
  int k3 = rem >> 5;
  int n0 = (rem & 31) * 32;
  const float* hp = out + HP_OFF;
  const float* R = (k3 == 0) ? R_p : (k3 == 1) ? R_mu : R_sg;
  #pragma unroll
  for (int t = 0; t < 8; ++t) {
    int idx = tid + t*128;          // float4 over 1024
    int r = idx >> 5, c4 = idx & 31;
    *(float4*)&hp_l[r*HP_S + c4*4] =
      *(const float4*)&hp[((size_t)(b*NNODES)+n0+r)*HDIM + c4*4];
  }
  __syncthreads();
  int cg = tid & 31, rg = tid >> 5;   // cols cg*4..+3, rows rg + 4*rr
  float acc[8][4];
  #pragma unroll
  for (int rr = 0; rr < 8; ++rr)
    #pragma unroll
    for (int c = 0; c < 4; ++c) acc[rr][c] = 0.f;
  for (int k4 = 0; k4 < 32; ++k4) {
    float w[4][4];
    #pragma unroll
    for (int kk = 0; kk < 4; ++kk) ld4(&R[(size_t)(k4*4+kk)*HDIM + cg*4], w[kk]);
    #pragma unroll
    for (int rr = 0; rr < 8; ++rr) {
      float hv[4];
      ld4(&hp_l[(rg + 4*rr)*HP_S + k4*4], hv);
      #pragma unroll
      for (int c = 0; c < 4; ++c) {
        float s = acc[rr][c];
        s = fmaf(hv[0], w[0][c], s);
        s = fmaf(hv[1], w[1][c], s);
        s = fmaf(hv[2], w[2][c], s);
        s = fmaf(hv[3], w[3][c], s);
        acc[rr][c] = s;
      }
    }
  }
  float* T = ws + WS_T;
  #pragma unroll
  for (int rr = 0; rr < 8; ++rr) {
    int row = rg + 4*rr;
    float4 o; o.x=acc[rr][0]; o.y=acc[rr][1]; o.z=acc[rr][2]; o.w=acc[rr][3];
    *(float4*)&T[((size_t)((b*3+k3)*NNODES)+n0+row)*HDIM + cg*4] = o;
  }
}

// ---------------- Kernel F: logits[b,n,m,0..2] fused over 3 decoders ----------
#define FT_S 132
__global__ __launch_bounds__(256) void k_logits(
    const float* __restrict__ ws, const float* __restrict__ out_hp, float* __restrict__ out)
{
  __shared__ float t_l[64*FT_S];    // 33.8KB
  __shared__ float hp_l[64*FT_S];   // 33.8KB
  int tid = threadIdx.x;
  int blk = blockIdx.x;
  int b = blk & 7;                  // XCD-local batch
  int rem = blk >> 3;               // 0..255
  int nt = rem >> 4, mt = rem & 15;
  int n0 = nt*64, m0 = mt*64;
  const float* hp = out_hp + HP_OFF;
  const float* T = ws + WS_T;
  #pragma unroll
  for (int t = 0; t < 8; ++t) {
    int idx = tid + t*256;
    int r = idx >> 5, c4 = idx & 31;
    *(float4*)&hp_l[r*FT_S + c4*4] =
      *(const float4*)&hp[((size_t)(b*NNODES)+m0+r)*HDIM + c4*4];
  }
  int ng = tid >> 4, mg = tid & 15;
  float lg[3][4][4];
  for (int k3 = 0; k3 < 3; ++k3) {
    __syncthreads();
    #pragma unroll
    for (int t = 0; t < 8; ++t) {
      int idx = tid + t*256;
      int r = idx >> 5, c4 = idx & 31;
      *(float4*)&t_l[r*FT_S + c4*4] =
        *(const float4*)&T[((size_t)((b*3+k3)*NNODES)+n0+r)*HDIM + c4*4];
    }
    __syncthreads();
    float acc[4][4];
    #pragma unroll
    for (int nn = 0; nn < 4; ++nn)
      #pragma unroll
      for (int mm = 0; mm < 4; ++mm) acc[nn][mm] = 0.f;
    for (int k4 = 0; k4 < 32; ++k4) {
      float tv[4][4], hv[4][4];
      #pragma unroll
      for (int nn = 0; nn < 4; ++nn) ld4(&t_l[(ng*4+nn)*FT_S + k4*4], tv[nn]);
      #pragma unroll
      for (int mm = 0; mm < 4; ++mm) ld4(&hp_l[(mg+16*mm)*FT_S + k4*4], hv[mm]);
      #pragma unroll
      for (int nn = 0; nn < 4; ++nn)
        #pragma unroll
        for (int mm = 0; mm < 4; ++mm) {
          float s = acc[nn][mm];
          s = fmaf(tv[nn][0], hv[mm][0], s);
          s = fmaf(tv[nn][1], hv[mm][1], s);
          s = fmaf(tv[nn][2], hv[mm][2], s);
          s = fmaf(tv[nn][3], hv[mm][3], s);
          acc[nn][mm] = s;
        }
    }
    #pragma unroll
    for (int nn = 0; nn < 4; ++nn)
      #pragma unroll
      for (int mm = 0; mm < 4; ++mm) lg[k3][nn][mm] = acc[nn][mm];
  }
  #pragma unroll
  for (int nn = 0; nn < 4; ++nn) {
    size_t base = ((size_t)(b*NNODES) + n0 + ng*4 + nn)*NNODES;
    #pragma unroll
    for (int mm = 0; mm < 4; ++mm) {
      size_t m = m0 + mg + 16*mm;
      float* po = &out[(base + m)*3];
      po[0] = lg[0][nn][mm];
      po[1] = lg[1][nn][mm];
      po[2] = lg[2][nn][mm];
    }
  }
}

extern "C" void kernel_launch(void* const* d_in, const int* in_sizes, int n_in,
                              void* d_out, int out_size, void* d_ws, size_t ws_size,
                              hipStream_t stream) {
  (void)in_sizes; (void)n_in; (void)out_size; (void)ws_size;
  const float* x        = (const float*)d_in[0];
  const float* a        = (const float*)d_in[1];
  const float* h        = (const float*)d_in[2];
  const float* Wk       = (const float*)d_in[3];
  const float* att_src  = (const float*)d_in[4];
  const float* att_dst  = (const float*)d_in[5];
  const float* bias_gat = (const float*)d_in[6];
  const float* b_u      = (const float*)d_in[7];
  const float* b_r      = (const float*)d_in[8];
  const float* b_c      = (const float*)d_in[9];
  const float* W_u      = (const float*)d_in[10];
  const float* W_r      = (const float*)d_in[11];
  const float* W_c      = (const float*)d_in[12];
  const float* R_p      = (const float*)d_in[13];
  const float* R_mu     = (const float*)d_in[14];
  const float* R_sg     = (const float*)d_in[15];
  float* out = (float*)d_out;
  float* ws  = (float*)d_ws;

  hipLaunchKernelGGL(k_hh_scores, dim3(1024), dim3(256), 0, stream,
                     x, Wk, att_src, att_dst, ws);
  hipLaunchKernelGGL(k_stats, dim3(8192), dim3(256), 0, stream, a, ws);
  hipLaunchKernelGGL(k_conv, dim3(512), dim3(256), 0, stream, a, bias_gat, ws);
  hipLaunchKernelGGL(k_gruA, dim3(512), dim3(256), 0, stream,
                     h, b_u, b_r, W_u, W_r, ws, out);
  hipLaunchKernelGGL(k_gruB, dim3(256), dim3(256), 0, stream,
                     h, b_c, W_c, ws, out);
  hipLaunchKernelGGL(k_T, dim3(768), dim3(128), 0, stream, R_p, R_mu, R_sg, out, ws);
  hipLaunchKernelGGL(k_logits, dim3(2048), dim3(256), 0, stream, ws, out, out);
}

// Round 5
// 168.486 us; speedup vs baseline: 3.8973x; 1.4922x over previous
//
#include <hip/hip_runtime.h>

#define BB 8
#define NNODES 1024
#define FIN 64
#define NH 4
#define NC 32
#define HDIM 128          // HIN == HID == 128
#define NEG_INF_F (-1e9f)

#define LOGITS_CNT (BB*NNODES*NNODES*3)   // 25165824
#define HP_OFF LOGITS_CNT

// scratch inside the (not-yet-written) logits region of d_out
#define U_OFF  0                      // u  [B*N][128]
#define RH_OFF (BB*NNODES*HDIM)       // rh [B*N][128]

// workspace layout (float offsets)
#define WS_HH    0
#define WS_SSRC  (WS_HH    + BB*NNODES*HDIM)   // [B][N][4]
#define WS_SDSTT (WS_SSRC  + BB*NNODES*NH)     // [B][4][N]
#define WS_M     (WS_SDSTT + BB*NH*NNODES)     // [B][N][4]
#define WS_RSUM  (WS_M     + BB*NNODES*NH)     // [B][N][4]
#define WS_CONV  (WS_RSUM  + BB*NNODES*NH)     // [B][N][128]
#define WS_T     (WS_CONV  + BB*NNODES*HDIM)   // region reused: TB bf16 + HPB bf16
// ushort offsets inside WS_T region:
//   TB : [B*3*N][128] bf16  (1,572,864 float-equiv)
//   HPB: [B*N][128]  bf16   (524,288 float-equiv), at ws + WS_T + 1572864
#define HPB_FOFF (WS_T + 1572864)

typedef float f32x4 __attribute__((ext_vector_type(4)));
typedef short bf16x8 __attribute__((ext_vector_type(8)));

__device__ __forceinline__ float sigmoidf_(float x) { return 1.0f/(1.0f+__expf(-x)); }
__device__ __forceinline__ float tanhf_(float x) {
  float e = __expf(2.0f*x); return 1.0f - 2.0f/(e+1.0f);
}
__device__ __forceinline__ void ld4(const float* p, float* d) {
  float4 v = *(const float4*)p;
  d[0]=v.x; d[1]=v.y; d[2]=v.z; d[3]=v.w;
}
__device__ __forceinline__ ushort f2b(float x) {
  union { float f; unsigned u; } v; v.f = x;
  unsigned r = v.u + 0x7fffu + ((v.u >> 16) & 1u);
  return (ushort)(r >> 16);
}

// ---------------- Kernel A: hh = x@Wk, per-node src/dst scores ----------------
__global__ __launch_bounds__(256) void k_hh_scores(
    const float* __restrict__ x, const float* __restrict__ Wk,
    const float* __restrict__ att_src, const float* __restrict__ att_dst,
    float* __restrict__ ws)
{
  __shared__ float wk_l[FIN*HDIM];   // 32KB
  __shared__ float x_l[8][FIN];      // 2KB
  int tid = threadIdx.x;
  int blk = blockIdx.x;
  int b = blk >> 7;
  int n0 = (blk & 127) * 8;
  #pragma unroll
  for (int t = 0; t < 8; ++t) {
    int idx = tid + t*256;
    int r = idx >> 5, c4 = idx & 31;
    *(float4*)&wk_l[r*HDIM + c4*4] = *(const float4*)&Wk[r*HDIM + c4*4];
  }
  if (tid < 128) {
    int r = tid >> 4, c4 = tid & 15;
    *(float4*)&x_l[r][c4*4] = *(const float4*)&x[((size_t)(b*NNODES)+n0+r)*FIN + c4*4];
  }
  __syncthreads();
  int col = tid & 127;
  int rh = tid >> 7;
  float as = att_src[col], ad = att_dst[col];
  float acc[4];
  #pragma unroll
  for (int rr = 0; rr < 4; ++rr) acc[rr] = 0.f;
  for (int k = 0; k < FIN; ++k) {
    float wv = wk_l[k*HDIM + col];
    #pragma unroll
    for (int rr = 0; rr < 4; ++rr)
      acc[rr] = fmaf(x_l[rh*4+rr][k], wv, acc[rr]);
  }
  float* hh    = ws + WS_HH;
  float* ssrc  = ws + WS_SSRC;
  float* sdstT = ws + WS_SDSTT;
  int hI = col >> 5;
  #pragma unroll
  for (int rr = 0; rr < 4; ++rr) {
    int n = n0 + rh*4 + rr;
    hh[((size_t)(b*NNODES)+n)*HDIM + col] = acc[rr];
    float ss = acc[rr]*as, sd = acc[rr]*ad;
    #pragma unroll
    for (int m = 16; m >= 1; m >>= 1) {
      ss += __shfl_xor(ss, m, 64);
      sd += __shfl_xor(sd, m, 64);
    }
    if ((col & 31) == 0) {
      ssrc[((size_t)(b*NNODES)+n)*NH + hI] = ss;
      sdstT[(size_t)(b*NH + hI)*NNODES + n] = sd;
    }
  }
}

// ---------------- Kernel B: softmax stats (max, 1/sum) per (b,i,h) ----------------
__global__ __launch_bounds__(256) void k_stats(
    const float* __restrict__ a, float* __restrict__ ws)
{
  __shared__ float a_l[NNODES];
  int tid = threadIdx.x;
  int blk = blockIdx.x;
  int b = blk & 7, i = blk >> 3;     // b-major on XCD
  const float* arow = a + ((size_t)(b*NNODES + i))*NNODES;
  *(float4*)&a_l[tid*4] = *(const float4*)&arow[tid*4];
  __syncthreads();
  int h = tid >> 6, lane = tid & 63;
  const float* ssrc  = ws + WS_SSRC;
  const float* sdstT = ws + WS_SDSTT;
  float si = ssrc[((size_t)(b*NNODES)+i)*NH + h];
  float e[16];
  float mx = -3.4e38f;
  #pragma unroll
  for (int t = 0; t < 16; ++t) {
    int j = lane + t*64;
    float s = si + sdstT[(size_t)(b*NH+h)*NNODES + j];
    float ev = s >= 0.f ? s : 0.2f*s;
    ev += NEG_INF_F * (1.0f - a_l[j]);
    e[t] = ev;
    mx = fmaxf(mx, ev);
  }
  #pragma unroll
  for (int m = 32; m >= 1; m >>= 1) mx = fmaxf(mx, __shfl_xor(mx, m, 64));
  float sum = 0.f;
  #pragma unroll
  for (int t = 0; t < 16; ++t) sum += __expf(e[t] - mx);
  #pragma unroll
  for (int m = 32; m >= 1; m >>= 1) sum += __shfl_xor(sum, m, 64);
  if (lane == 0) {
    ws[WS_M    + ((size_t)(b*NNODES)+i)*NH + h] = mx;
    ws[WS_RSUM + ((size_t)(b*NNODES)+i)*NH + h] = 1.0f / sum;
  }
}

// ---------------- Kernel C: conv = softmax(e) @ hh, + bias ----------------
#define CBM 16
#define P_HS 66
#define P_RS 268
__global__ __launch_bounds__(256) void k_conv(
    const float* __restrict__ a, const float* __restrict__ bias_gat,
    float* __restrict__ ws)
{
  __shared__ float hh_l[64*HDIM];      // 32KB
  __shared__ float p_l[CBM][P_RS];     // 17.2KB
  __shared__ float aT[CBM][64];        // 4KB
  __shared__ float ssrc_l[CBM][4], m_l[CBM][4], rs_l[CBM][4];
  int tid = threadIdx.x;
  int blk = blockIdx.x;
  int b = blk & 7;                     // XCD-local batch
  int i0 = (blk >> 3) * CBM;
  const float* hh    = ws + WS_HH;
  const float* sdstT = ws + WS_SDSTT;
  if (tid < 64) {
    int r = tid >> 2, h = tid & 3;
    ssrc_l[r][h] = ws[WS_SSRC + ((size_t)(b*NNODES)+i0+r)*NH + h];
    m_l[r][h]    = ws[WS_M    + ((size_t)(b*NNODES)+i0+r)*NH + h];
    rs_l[r][h]   = ws[WS_RSUM + ((size_t)(b*NNODES)+i0+r)*NH + h];
  }
  int jj = tid & 63, hF = tid >> 6;
  int col4 = tid & 31, rg = tid >> 5;
  int h2 = col4 >> 3;
  float acc[2][4];
  #pragma unroll
  for (int r = 0; r < 2; ++r)
    #pragma unroll
    for (int c = 0; c < 4; ++c) acc[r][c] = 0.f;
  __syncthreads();
  for (int jt = 0; jt < 16; ++jt) {
    int j0 = jt * 64;
    #pragma unroll
    for (int t = 0; t < 8; ++t) {
      int idx = tid + t*256;
      int r = idx >> 5, c4 = idx & 31;
      *(float4*)&hh_l[r*HDIM + c4*4] =
        *(const float4*)&hh[((size_t)(b*NNODES) + j0 + r)*HDIM + c4*4];
    }
    {
      int r = tid >> 4, jq = tid & 15;
      *(float4*)&aT[r][jq*4] =
        *(const float4*)&a[((size_t)(b*NNODES) + i0 + r)*NNODES + j0 + jq*4];
    }
    float sd = sdstT[(size_t)(b*NH + hF)*NNODES + j0 + jj];
    __syncthreads();
    #pragma unroll 4
    for (int r = 0; r < CBM; ++r) {
      float s = ssrc_l[r][hF] + sd;
      float ev = s >= 0.f ? s : 0.2f*s;
      ev += NEG_INF_F*(1.0f - aT[r][jj]);
      p_l[r][hF*P_HS + jj] = __expf(ev - m_l[r][hF]) * rs_l[r][hF];
    }
    __syncthreads();
    for (int j = 0; j < 64; ++j) {
      float hv[4];
      ld4(&hh_l[j*HDIM + col4*4], hv);
      #pragma unroll
      for (int rr = 0; rr < 2; ++rr) {
        float pv = p_l[rg*2+rr][h2*P_HS + j];
        #pragma unroll
        for (int c = 0; c < 4; ++c)
          acc[rr][c] = fmaf(pv, hv[c], acc[rr][c]);
      }
    }
    __syncthreads();
  }
  float bias[4];
  ld4(&bias_gat[col4*4], bias);
  float* conv = ws + WS_CONV;
  #pragma unroll
  for (int rr = 0; rr < 2; ++rr) {
    int n = i0 + rg*2 + rr;
    float4 o;
    o.x = acc[rr][0] + bias[0]; o.y = acc[rr][1] + bias[1];
    o.z = acc[rr][2] + bias[2]; o.w = acc[rr][3] + bias[3];
    *(float4*)&conv[((size_t)(b*NNODES) + n)*HDIM + col4*4] = o;
  }
}

// ---------------- Kernel D1: u and r*h via tiled GEMM (BM64 BN64 BK32) -------
__global__ __launch_bounds__(256) void k_gruA(
    const float* __restrict__ h_in,
    const float* __restrict__ b_u, const float* __restrict__ b_r,
    const float* __restrict__ W_u, const float* __restrict__ W_r,
    const float* __restrict__ ws, float* __restrict__ out)
{
  __shared__ float a_l[64][36];
  __shared__ float w_l[32][64];
  int tid = threadIdx.x;
  int blk = blockIdx.x;
  int g = blk & 1;
  int ntile = (blk >> 1) & 1;
  int mbase = (blk >> 2) * 64;
  const float* conv = ws + WS_CONV;
  const float* Wg = g ? W_r : W_u;
  int ncol0 = ntile * 64;
  int rg = tid >> 4, cg = tid & 15;
  int col0 = cg * 4;
  float acc[4][4] = {{0.f}};
  for (int kc = 0; kc < 8; ++kc) {
    const float* abase = (kc < 4) ? conv : h_in;
    int coff = (kc & 3) * 32;
    __syncthreads();
    #pragma unroll
    for (int t = 0; t < 2; ++t) {
      int idx = tid + t*256;
      int r = idx >> 3, q = idx & 7;
      *(float4*)&a_l[r][q*4] =
        *(const float4*)&abase[(size_t)(mbase + r)*HDIM + coff + q*4];
    }
    #pragma unroll
    for (int t = 0; t < 2; ++t) {
      int idx = tid + t*256;
      int r = idx >> 4, q = idx & 15;
      *(float4*)&w_l[r][q*4] =
        *(const float4*)&Wg[(size_t)(kc*32 + r)*HDIM + ncol0 + q*4];
    }
    __syncthreads();
    for (int k = 0; k < 32; ++k) {
      float4 wv = *(const float4*)&w_l[k][col0];
      #pragma unroll
      for (int rr = 0; rr < 4; ++rr) {
        float av = a_l[rg*4+rr][k];
        acc[rr][0] = fmaf(av, wv.x, acc[rr][0]);
        acc[rr][1] = fmaf(av, wv.y, acc[rr][1]);
        acc[rr][2] = fmaf(av, wv.z, acc[rr][2]);
        acc[rr][3] = fmaf(av, wv.w, acc[rr][3]);
      }
    }
  }
  #pragma unroll
  for (int rr = 0; rr < 4; ++rr) {
    int m = mbase + rg*4 + rr;
    int n = m & (NNODES-1);
    float4 o;
    if (g == 0) {
      float bv = b_u[n];
      o.x = sigmoidf_(bv + acc[rr][0]);
      o.y = sigmoidf_(bv + acc[rr][1]);
      o.z = sigmoidf_(bv + acc[rr][2]);
      o.w = sigmoidf_(bv + acc[rr][3]);
      *(float4*)&out[U_OFF + (size_t)m*HDIM + ncol0 + col0] = o;
    } else {
      float bv = b_r[n];
      float4 hv = *(const float4*)&h_in[(size_t)m*HDIM + ncol0 + col0];
      o.x = sigmoidf_(bv + acc[rr][0]) * hv.x;
      o.y = sigmoidf_(bv + acc[rr][1]) * hv.y;
      o.z = sigmoidf_(bv + acc[rr][2]) * hv.z;
      o.w = sigmoidf_(bv + acc[rr][3]) * hv.w;
      *(float4*)&out[RH_OFF + (size_t)m*HDIM + ncol0 + col0] = o;
    }
  }
}

// ---------------- Kernel D2: c-gate GEMM + final h' (+ bf16 h' copy) ---------
__global__ __launch_bounds__(256) void k_gruB(
    const float* __restrict__ h_in, const float* __restrict__ b_c,
    const float* __restrict__ W_c,
    float* __restrict__ ws, float* __restrict__ out)
{
  __shared__ float a_l[64][36];
  __shared__ float w_l[32][64];
  int tid = threadIdx.x;
  int blk = blockIdx.x;
  int ntile = blk & 1;
  int mbase = (blk >> 1) * 64;
  const float* conv = ws + WS_CONV;
  const float* rh   = out + RH_OFF;
  ushort* HPB = (ushort*)(ws + HPB_FOFF);
  int ncol0 = ntile * 64;
  int rg = tid >> 4, cg = tid & 15;
  int col0 = cg * 4;
  float acc[4][4] = {{0.f}};
  for (int kc = 0; kc < 8; ++kc) {
    const float* abase = (kc < 4) ? conv : rh;
    int coff = (kc & 3) * 32;
    __syncthreads();
    #pragma unroll
    for (int t = 0; t < 2; ++t) {
      int idx = tid + t*256;
      int r = idx >> 3, q = idx & 7;
      *(float4*)&a_l[r][q*4] =
        *(const float4*)&abase[(size_t)(mbase + r)*HDIM + coff + q*4];
    }
    #pragma unroll
    for (int t = 0; t < 2; ++t) {
      int idx = tid + t*256;
      int r = idx >> 4, q = idx & 15;
      *(float4*)&w_l[r][q*4] =
        *(const float4*)&W_c[(size_t)(kc*32 + r)*HDIM + ncol0 + q*4];
    }
    __syncthreads();
    for (int k = 0; k < 32; ++k) {
      float4 wv = *(const float4*)&w_l[k][col0];
      #pragma unroll
      for (int rr = 0; rr < 4; ++rr) {
        float av = a_l[rg*4+rr][k];
        acc[rr][0] = fmaf(av, wv.x, acc[rr][0]);
        acc[rr][1] = fmaf(av, wv.y, acc[rr][1]);
        acc[rr][2] = fmaf(av, wv.z, acc[rr][2]);
        acc[rr][3] = fmaf(av, wv.w, acc[rr][3]);
      }
    }
  }
  #pragma unroll
  for (int rr = 0; rr < 4; ++rr) {
    int m = mbase + rg*4 + rr;
    int n = m & (NNODES-1);
    float bv = b_c[n];
    float4 uv = *(const float4*)&out[U_OFF + (size_t)m*HDIM + ncol0 + col0];
    float4 hv = *(const float4*)&h_in[(size_t)m*HDIM + ncol0 + col0];
    float4 o;
    o.x = uv.x*hv.x + (1.0f-uv.x)*tanhf_(bv + acc[rr][0]);
    o.y = uv.y*hv.y + (1.0f-uv.y)*tanhf_(bv + acc[rr][1]);
    o.z = uv.z*hv.z + (1.0f-uv.z)*tanhf_(bv + acc[rr][2]);
    o.w = uv.w*hv.w + (1.0f-uv.w)*tanhf_(bv + acc[rr][3]);
    *(float4*)&out[HP_OFF + (size_t)m*HDIM + ncol0 + col0] = o;
    ushort4 ob;
    ob.x = f2b(o.x); ob.y = f2b(o.y); ob.z = f2b(o.z); ob.w = f2b(o.w);
    *(ushort4*)&HPB[(size_t)m*HDIM + ncol0 + col0] = ob;
  }
}

// ---------------- Kernel E: T[b][k3] = h' @ R_k3 (f32 compute, bf16 store) ---
#define HP_S 132
__global__ __launch_bounds__(128) void k_T(
    const float* __restrict__ R_p, const float* __restrict__ R_mu, const float* __restrict__ R_sg,
    const float* __restrict__ out, float* __restrict__ ws)
{
  __shared__ float hp_l[32*HP_S];
  int tid = threadIdx.x;
  int blk = blockIdx.x;
  int b = blk & 7;                 // XCD-local batch
  int rem = blk >> 3;              // 0..95
  int k3 = rem >> 5;
  int n0 = (rem & 31) * 32;
  const float* hp = out + HP_OFF;
  const float* R = (k3 == 0) ? R_p : (k3 == 1) ? R_mu : R_sg;
  #pragma unroll
  for (int t = 0; t < 8; ++t) {
    int idx = tid + t*128;
    int r = idx >> 5, c4 = idx & 31;
    *(float4*)&hp_l[r*HP_S + c4*4] =
      *(const float4*)&hp[((size_t)(b*NNODES)+n0+r)*HDIM + c4*4];
  }
  __syncthreads();
  int cg = tid & 31, rg = tid >> 5;
  float acc[8][4];
  #pragma unroll
  for (int rr = 0; rr < 8; ++rr)
    #pragma unroll
    for (int c = 0; c < 4; ++c) acc[rr][c] = 0.f;
  for (int k4 = 0; k4 < 32; ++k4) {
    float w[4][4];
    #pragma unroll
    for (int kk = 0; kk < 4; ++kk) ld4(&R[(size_t)(k4*4+kk)*HDIM + cg*4], w[kk]);
    #pragma unroll
    for (int rr = 0; rr < 8; ++rr) {
      float hv[4];
      ld4(&hp_l[(rg + 4*rr)*HP_S + k4*4], hv);
      #pragma unroll
      for (int c = 0; c < 4; ++c) {
        float s = acc[rr][c];
        s = fmaf(hv[0], w[0][c], s);
        s = fmaf(hv[1], w[1][c], s);
        s = fmaf(hv[2], w[2][c], s);
        s = fmaf(hv[3], w[3][c], s);
        acc[rr][c] = s;
      }
    }
  }
  ushort* TB = (ushort*)(ws + WS_T);
  #pragma unroll
  for (int rr = 0; rr < 8; ++rr) {
    int row = rg + 4*rr;
    ushort4 o;
    o.x = f2b(acc[rr][0]); o.y = f2b(acc[rr][1]);
    o.z = f2b(acc[rr][2]); o.w = f2b(acc[rr][3]);
    *(ushort4*)&TB[((size_t)((b*3+k3)*NNODES)+n0+row)*HDIM + cg*4] = o;
  }
}

// ---------------- Kernel F: logits via bf16 MFMA, 3 decoders fused ----------
// 64x64 tile per block, 4 waves each own 32x32 x 3 decoders.
#define LT_S 136   // bf16 row stride (272B): 2-way bank aliasing only
__global__ __launch_bounds__(256) void k_logits_m(
    const float* __restrict__ ws, float* __restrict__ out)
{
  __shared__ ushort t_b[3][64*LT_S];   // 52224 B
  __shared__ ushort hp_b[64*LT_S];     // 17408 B
  const ushort* TB  = (const ushort*)(ws + WS_T);
  const ushort* HPB = (const ushort*)(ws + HPB_FOFF);
  int tid = threadIdx.x;
  int blk = blockIdx.x;
  int b = blk & 7;                  // XCD-local batch
  int rem = blk >> 3;               // 0..255
  int nt = rem >> 4, mt = rem & 15;
  int n0 = nt*64, m0 = mt*64;
  // stage hp tile [64][128] bf16
  #pragma unroll
  for (int t = 0; t < 4; ++t) {
    int idx = tid + t*256;
    int r = idx >> 4, c = idx & 15;
    *(uint4*)&hp_b[r*LT_S + c*8] =
      *(const uint4*)&HPB[((size_t)(b*NNODES)+m0+r)*HDIM + c*8];
  }
  // stage 3 T tiles [64][128] bf16
  #pragma unroll
  for (int t = 0; t < 12; ++t) {
    int idx = tid + t*256;
    int k3 = idx >> 10, r = (idx >> 4) & 63, c = idx & 15;
    *(uint4*)&t_b[k3][r*LT_S + c*8] =
      *(const uint4*)&TB[((size_t)((b*3+k3)*NNODES)+n0+r)*HDIM + c*8];
  }
  __syncthreads();
  int w = tid >> 6, lane = tid & 63;
  int nbase = (w >> 1) * 32, mbase = (w & 1) * 32;
  int frow = lane & 15, fk = (lane >> 4) * 8;
  f32x4 acc[3][2][2];
  #pragma unroll
  for (int k3 = 0; k3 < 3; ++k3)
    #pragma unroll
    for (int nn = 0; nn < 2; ++nn)
      #pragma unroll
      for (int mm = 0; mm < 2; ++mm) acc[k3][nn][mm] = (f32x4)0.f;
  #pragma unroll
  for (int ks = 0; ks < 4; ++ks) {
    int ko = ks*32 + fk;
    bf16x8 bfr[2];
    #pragma unroll
    for (int mm = 0; mm < 2; ++mm)
      bfr[mm] = *(const bf16x8*)&hp_b[(mbase + mm*16 + frow)*LT_S + ko];
    #pragma unroll
    for (int k3 = 0; k3 < 3; ++k3)
      #pragma unroll
      for (int nn = 0; nn < 2; ++nn) {
        bf16x8 afr = *(const bf16x8*)&t_b[k3][(nbase + nn*16 + frow)*LT_S + ko];
        #pragma unroll
        for (int mm = 0; mm < 2; ++mm)
          acc[k3][nn][mm] = __builtin_amdgcn_mfma_f32_16x16x32_bf16(
              afr, bfr[mm], acc[k3][nn][mm], 0, 0, 0);
      }
  }
  // epilogue: C/D layout col=lane&15, row=(lane>>4)*4+reg
  int crow = (lane >> 4) * 4, ccol = lane & 15;
  #pragma unroll
  for (int nn = 0; nn < 2; ++nn)
    #pragma unroll
    for (int mm = 0; mm < 2; ++mm)
      #pragma unroll
      for (int r = 0; r < 4; ++r) {
        int n = n0 + nbase + nn*16 + crow + r;
        int m = m0 + mbase + mm*16 + ccol;
        float* po = &out[(((size_t)(b*NNODES) + n)*NNODES + m)*3];
        po[0] = acc[0][nn][mm][r];
        po[1] = acc[1][nn][mm][r];
        po[2] = acc[2][nn][mm][r];
      }
}

extern "C" void kernel_launch(void* const* d_in, const int* in_sizes, int n_in,
                              void* d_out, int out_size, void* d_ws, size_t ws_size,
                              hipStream_t stream) {
  (void)in_sizes; (void)n_in; (void)out_size; (void)ws_size;
  const float* x        = (const float*)d_in[0];
  const float* a        = (const float*)d_in[1];
  const float* h        = (const float*)d_in[2];
  const float* Wk       = (const float*)d_in[3];
  const float* att_src  = (const float*)d_in[4];
  const float* att_dst  = (const float*)d_in[5];
  const float* bias_gat = (const float*)d_in[6];
  const float* b_u      = (const float*)d_in[7];
  const float* b_r      = (const float*)d_in[8];
  const float* b_c      = (const float*)d_in[9];
  const float* W_u      = (const float*)d_in[10];
  const float* W_r      = (const float*)d_in[11];
  const float* W_c      = (const float*)d_in[12];
  const float* R_p      = (const float*)d_in[13];
  const float* R_mu     = (const float*)d_in[14];
  const float* R_sg     = (const float*)d_in[15];
  float* out = (float*)d_out;
  float* ws  = (float*)d_ws;

  hipLaunchKernelGGL(k_hh_scores, dim3(1024), dim3(256), 0, stream,
                     x, Wk, att_src, att_dst, ws);
  hipLaunchKernelGGL(k_stats, dim3(8192), dim3(256), 0, stream, a, ws);
  hipLaunchKernelGGL(k_conv, dim3(512), dim3(256), 0, stream, a, bias_gat, ws);
  hipLaunchKernelGGL(k_gruA, dim3(512), dim3(256), 0, stream,
                     h, b_u, b_r, W_u, W_r, ws, out);
  hipLaunchKernelGGL(k_gruB, dim3(256), dim3(256), 0, stream,
                     h, b_c, W_c, ws, out);
  hipLaunchKernelGGL(k_T, dim3(768), dim3(128), 0, stream, R_p, R_mu, R_sg, out, ws);
  hipLaunchKernelGGL(k_logits_m, dim3(2048), dim3(256), 0, stream, ws, out);
}

// Round 6
// 142.212 us; speedup vs baseline: 4.6173x; 1.1848x over previous
//
#include <hip/hip_runtime.h>

#define BB 8
#define NNODES 1024
#define FIN 64
#define NH 4
#define NC 32
#define HDIM 128          // HIN == HID == 128
#define NEG_INF_F (-1e9f)

#define LOGITS_CNT (BB*NNODES*NNODES*3)   // 25165824
#define HP_OFF LOGITS_CNT

// scratch inside the (not-yet-written) logits region of d_out
#define U_OFF    0                        // u        [B*N][128] f32
#define RH_OFF   (BB*NNODES*HDIM)         // r*h      [B*N][128] f32
#define CP1_OFF  (2*BB*NNODES*HDIM)       // conv partial (j-half 1) f32
#define HHTB_OFF (3*BB*NNODES*HDIM)       // hh^T bf16 [B][128][N] (as ushort)

// workspace layout (float offsets)
#define WS_HH    0                               // (dead region, kept for layout)
#define WS_SSRC  (WS_HH    + BB*NNODES*HDIM)     // [B][N][4]
#define WS_SDSTT (WS_SSRC  + BB*NNODES*NH)       // [B][4][N]
#define WS_M     (WS_SDSTT + BB*NH*NNODES)       // [B][N][4]
#define WS_RSUM  (WS_M     + BB*NNODES*NH)       // [B][N][4]
#define WS_CONV  (WS_RSUM  + BB*NNODES*NH)       // conv partial (j-half 0) f32
#define WS_T     (WS_CONV  + BB*NNODES*HDIM)     // TB bf16 + HPB bf16
#define HPB_FOFF (WS_T + 1572864)

typedef float f32x4 __attribute__((ext_vector_type(4)));
typedef short bf16x8 __attribute__((ext_vector_type(8)));

__device__ __forceinline__ float sigmoidf_(float x) { return 1.0f/(1.0f+__expf(-x)); }
__device__ __forceinline__ float tanhf_(float x) {
  float e = __expf(2.0f*x); return 1.0f - 2.0f/(e+1.0f);
}
__device__ __forceinline__ void ld4(const float* p, float* d) {
  float4 v = *(const float4*)p;
  d[0]=v.x; d[1]=v.y; d[2]=v.z; d[3]=v.w;
}
__device__ __forceinline__ ushort f2b(float x) {
  union { float f; unsigned u; } v; v.f = x;
  unsigned r = v.u + 0x7fffu + ((v.u >> 16) & 1u);
  return (ushort)(r >> 16);
}

// ---------------- Kernel A: scores + hh^T(bf16) ----------------
__global__ __launch_bounds__(256) void k_hh_scores(
    const float* __restrict__ x, const float* __restrict__ Wk,
    const float* __restrict__ att_src, const float* __restrict__ att_dst,
    float* __restrict__ ws, float* __restrict__ out)
{
  __shared__ float wk_l[FIN*HDIM];   // 32KB
  __shared__ float x_l[8][FIN];      // 2KB
  int tid = threadIdx.x;
  int blk = blockIdx.x;
  int b = blk >> 7;
  int n0 = (blk & 127) * 8;
  #pragma unroll
  for (int t = 0; t < 8; ++t) {
    int idx = tid + t*256;
    int r = idx >> 5, c4 = idx & 31;
    *(float4*)&wk_l[r*HDIM + c4*4] = *(const float4*)&Wk[r*HDIM + c4*4];
  }
  if (tid < 128) {
    int r = tid >> 4, c4 = tid & 15;
    *(float4*)&x_l[r][c4*4] = *(const float4*)&x[((size_t)(b*NNODES)+n0+r)*FIN + c4*4];
  }
  __syncthreads();
  int col = tid & 127;
  int rh = tid >> 7;
  float as = att_src[col], ad = att_dst[col];
  float acc[4];
  #pragma unroll
  for (int rr = 0; rr < 4; ++rr) acc[rr] = 0.f;
  for (int k = 0; k < FIN; ++k) {
    float wv = wk_l[k*HDIM + col];
    #pragma unroll
    for (int rr = 0; rr < 4; ++rr)
      acc[rr] = fmaf(x_l[rh*4+rr][k], wv, acc[rr]);
  }
  float* ssrc  = ws + WS_SSRC;
  float* sdstT = ws + WS_SDSTT;
  ushort* HHTB = (ushort*)(out + HHTB_OFF);
  int hI = col >> 5;
  #pragma unroll
  for (int rr = 0; rr < 4; ++rr) {
    int n = n0 + rh*4 + rr;
    HHTB[((size_t)(b*HDIM)+col)*NNODES + n] = f2b(acc[rr]);
    float ss = acc[rr]*as, sd = acc[rr]*ad;
    #pragma unroll
    for (int m = 16; m >= 1; m >>= 1) {
      ss += __shfl_xor(ss, m, 64);
      sd += __shfl_xor(sd, m, 64);
    }
    if ((col & 31) == 0) {
      ssrc[((size_t)(b*NNODES)+n)*NH + hI] = ss;
      sdstT[(size_t)(b*NH + hI)*NNODES + n] = sd;
    }
  }
}

// ---------------- Kernel B: softmax stats (max, 1/sum) per (b,i,h) ----------------
__global__ __launch_bounds__(256) void k_stats(
    const float* __restrict__ a, float* __restrict__ ws)
{
  __shared__ float a_l[NNODES];
  int tid = threadIdx.x;
  int blk = blockIdx.x;
  int b = blk & 7, i = blk >> 3;     // b-major on XCD
  const float* arow = a + ((size_t)(b*NNODES + i))*NNODES;
  *(float4*)&a_l[tid*4] = *(const float4*)&arow[tid*4];
  __syncthreads();
  int h = tid >> 6, lane = tid & 63;
  const float* ssrc  = ws + WS_SSRC;
  const float* sdstT = ws + WS_SDSTT;
  float si = ssrc[((size_t)(b*NNODES)+i)*NH + h];
  float e[16];
  float mx = -3.4e38f;
  #pragma unroll
  for (int t = 0; t < 16; ++t) {
    int j = lane + t*64;
    float s = si + sdstT[(size_t)(b*NH+h)*NNODES + j];
    float ev = s >= 0.f ? s : 0.2f*s;
    ev += NEG_INF_F * (1.0f - a_l[j]);
    e[t] = ev;
    mx = fmaxf(mx, ev);
  }
  #pragma unroll
  for (int m = 32; m >= 1; m >>= 1) mx = fmaxf(mx, __shfl_xor(mx, m, 64));
  float sum = 0.f;
  #pragma unroll
  for (int t = 0; t < 16; ++t) sum += __expf(e[t] - mx);
  #pragma unroll
  for (int m = 32; m >= 1; m >>= 1) sum += __shfl_xor(sum, m, 64);
  if (lane == 0) {
    ws[WS_M    + ((size_t)(b*NNODES)+i)*NH + h] = mx;
    ws[WS_RSUM + ((size_t)(b*NNODES)+i)*NH + h] = 1.0f / sum;
  }
}

// ---------------- Kernel C: conv = softmax(e) @ hh via bf16 MFMA -------------
// grid 256: b = blk&7, it = (blk>>3)>>1 (64-row i-tile), jh = (blk>>3)&1 (j half)
// 4 waves; wave w owns rows i0+w*16..+15, all 4 heads, 128 cols.
#define HT_S 40   // bf16 row stride for hhT chunk (80B: 2-way bank alias, free)
__global__ __launch_bounds__(256) void k_conv_m(
    const float* __restrict__ a,
    float* __restrict__ ws, float* __restrict__ out)
{
  __shared__ ushort hhT_l[128*HT_S];   // 10240 B
  __shared__ float sdst_l[4*32];       // 512 B
  int tid = threadIdx.x;
  int blk = blockIdx.x;
  int b = blk & 7;
  int rem = blk >> 3;
  int it = rem >> 1, jh = rem & 1;
  int i0 = it * 64;
  int j0b = jh * 512;
  int w = tid >> 6, lane = tid & 63;
  int i0w = i0 + w * 16;
  int i = i0w + (lane & 15);
  int koff = (lane >> 4) * 8;
  const ushort* HHTB = (const ushort*)(out + HHTB_OFF);
  const float* sdstT = ws + WS_SDSTT;
  float4 ss4 = *(const float4*)&ws[WS_SSRC + ((size_t)(b*NNODES)+i)*4];
  float4 m4  = *(const float4*)&ws[WS_M    + ((size_t)(b*NNODES)+i)*4];
  float4 rs4 = *(const float4*)&ws[WS_RSUM + ((size_t)(b*NNODES)+i)*4];
  float ssv[4] = {ss4.x, ss4.y, ss4.z, ss4.w};
  float mv[4]  = {m4.x,  m4.y,  m4.z,  m4.w};
  float rsv[4] = {rs4.x, rs4.y, rs4.z, rs4.w};
  f32x4 acc[4][2];
  #pragma unroll
  for (int h = 0; h < 4; ++h)
    #pragma unroll
    for (int cf = 0; cf < 2; ++cf) acc[h][cf] = (f32x4)0.f;
  const float* arow = a + ((size_t)(b*NNODES)+i)*NNODES;
  for (int ch = 0; ch < 16; ++ch) {
    int j0 = j0b + ch*32;
    // stage hhT chunk [128 c][32 j] bf16
    #pragma unroll
    for (int s = 0; s < 2; ++s) {
      int seg = tid + s*256;
      int c = seg >> 2, q = seg & 3;
      *(uint4*)&hhT_l[c*HT_S + q*8] =
        *(const uint4*)&HHTB[((size_t)(b*HDIM)+c)*NNODES + j0 + q*8];
    }
    if (tid < 32) {
      int h = tid >> 3, q = tid & 7;
      *(float4*)&sdst_l[h*32 + q*4] =
        *(const float4*)&sdstT[(size_t)(b*NH + h)*NNODES + j0 + q*4];
    }
    float av[8];
    {
      float4 a0 = *(const float4*)&arow[j0 + koff];
      float4 a1 = *(const float4*)&arow[j0 + koff + 4];
      av[0]=a0.x; av[1]=a0.y; av[2]=a0.z; av[3]=a0.w;
      av[4]=a1.x; av[5]=a1.y; av[6]=a1.z; av[7]=a1.w;
    }
    __syncthreads();
    float am[8];
    #pragma unroll
    for (int t = 0; t < 8; ++t) am[t] = fmaf(av[t], 1e9f, -1e9f);
    #pragma unroll
    for (int h = 0; h < 4; ++h) {
      float sd[8];
      ld4(&sdst_l[h*32 + koff], sd);
      ld4(&sdst_l[h*32 + koff + 4], sd + 4);
      bf16x8 pf;
      #pragma unroll
      for (int t = 0; t < 8; ++t) {
        float s = ssv[h] + sd[t];
        s = fmaxf(s, 0.2f*s);
        float p = __expf(s + am[t] - mv[h]) * rsv[h];
        pf[t] = (short)f2b(p);
      }
      #pragma unroll
      for (int cf = 0; cf < 2; ++cf) {
        int c = h*32 + cf*16 + (lane & 15);
        bf16x8 bfr = *(const bf16x8*)&hhT_l[c*HT_S + koff];
        acc[h][cf] = __builtin_amdgcn_mfma_f32_16x16x32_bf16(
            pf, bfr, acc[h][cf], 0, 0, 0);
      }
    }
    __syncthreads();
  }
  float* cp = jh ? (out + CP1_OFF) : (ws + WS_CONV);
  int crow = (lane >> 4) * 4, ccol = lane & 15;
  #pragma unroll
  for (int h = 0; h < 4; ++h)
    #pragma unroll
    for (int cf = 0; cf < 2; ++cf)
      #pragma unroll
      for (int r = 0; r < 4; ++r)
        cp[((size_t)(b*NNODES) + i0w + crow + r)*HDIM + h*32 + cf*16 + ccol]
          = acc[h][cf][r];
}

// ---------------- Kernel D1: u and r*h via tiled GEMM (BM64 BN64 BK32) -------
__global__ __launch_bounds__(256) void k_gruA(
    const float* __restrict__ h_in,
    const float* __restrict__ b_u, const float* __restrict__ b_r,
    const float* __restrict__ W_u, const float* __restrict__ W_r,
    const float* __restrict__ bias_gat,
    const float* __restrict__ ws, float* __restrict__ out)
{
  __shared__ float a_l[64][36];
  __shared__ float w_l[32][64];
  int tid = threadIdx.x;
  int blk = blockIdx.x;
  int g = blk & 1;
  int ntile = (blk >> 1) & 1;
  int mbase = (blk >> 2) * 64;
  const float* conv0 = ws + WS_CONV;
  const float* conv1 = out + CP1_OFF;
  const float* Wg = g ? W_r : W_u;
  int ncol0 = ntile * 64;
  int rg = tid >> 4, cg = tid & 15;
  int col0 = cg * 4;
  float acc[4][4] = {{0.f}};
  for (int kc = 0; kc < 8; ++kc) {
    int coff = (kc & 3) * 32;
    __syncthreads();
    #pragma unroll
    for (int t = 0; t < 2; ++t) {
      int idx = tid + t*256;
      int r = idx >> 3, q = idx & 7;
      float4 v;
      if (kc < 4) {
        float4 v0 = *(const float4*)&conv0[(size_t)(mbase + r)*HDIM + coff + q*4];
        float4 v1 = *(const float4*)&conv1[(size_t)(mbase + r)*HDIM + coff + q*4];
        float4 bv = *(const float4*)&bias_gat[coff + q*4];
        v.x = v0.x+v1.x+bv.x; v.y = v0.y+v1.y+bv.y;
        v.z = v0.z+v1.z+bv.z; v.w = v0.w+v1.w+bv.w;
      } else {
        v = *(const float4*)&h_in[(size_t)(mbase + r)*HDIM + coff + q*4];
      }
      *(float4*)&a_l[r][q*4] = v;
    }
    #pragma unroll
    for (int t = 0; t < 2; ++t) {
      int idx = tid + t*256;
      int r = idx >> 4, q = idx & 15;
      *(float4*)&w_l[r][q*4] =
        *(const float4*)&Wg[(size_t)(kc*32 + r)*HDIM + ncol0 + q*4];
    }
    __syncthreads();
    for (int k = 0; k < 32; ++k) {
      float4 wv = *(const float4*)&w_l[k][col0];
      #pragma unroll
      for (int rr = 0; rr < 4; ++rr) {
        float av = a_l[rg*4+rr][k];
        acc[rr][0] = fmaf(av, wv.x, acc[rr][0]);
        acc[rr][1] = fmaf(av, wv.y, acc[rr][1]);
        acc[rr][2] = fmaf(av, wv.z, acc[rr][2]);
        acc[rr][3] = fmaf(av, wv.w, acc[rr][3]);
      }
    }
  }
  #pragma unroll
  for (int rr = 0; rr < 4; ++rr) {
    int m = mbase + rg*4 + rr;
    int n = m & (NNODES-1);
    float4 o;
    if (g == 0) {
      float bv = b_u[n];
      o.x = sigmoidf_(bv + acc[rr][0]);
      o.y = sigmoidf_(bv + acc[rr][1]);
      o.z = sigmoidf_(bv + acc[rr][2]);
      o.w = sigmoidf_(bv + acc[rr][3]);
      *(float4*)&out[U_OFF + (size_t)m*HDIM + ncol0 + col0] = o;
    } else {
      float bv = b_r[n];
      float4 hv = *(const float4*)&h_in[(size_t)m*HDIM + ncol0 + col0];
      o.x = sigmoidf_(bv + acc[rr][0]) * hv.x;
      o.y = sigmoidf_(bv + acc[rr][1]) * hv.y;
      o.z = sigmoidf_(bv + acc[rr][2]) * hv.z;
      o.w = sigmoidf_(bv + acc[rr][3]) * hv.w;
      *(float4*)&out[RH_OFF + (size_t)m*HDIM + ncol0 + col0] = o;
    }
  }
}

// ---------------- Kernel D2: c-gate GEMM + final h' (+ bf16 h' copy) ---------
__global__ __launch_bounds__(256) void k_gruB(
    const float* __restrict__ h_in, const float* __restrict__ b_c,
    const float* __restrict__ W_c, const float* __restrict__ bias_gat,
    float* __restrict__ ws, float* __restrict__ out)
{
  __shared__ float a_l[64][36];
  __shared__ float w_l[32][64];
  int tid = threadIdx.x;
  int blk = blockIdx.x;
  int ntile = blk & 1;
  int mbase = (blk >> 1) * 64;
  const float* conv0 = ws + WS_CONV;
  const float* conv1 = out + CP1_OFF;
  const float* rh   = out + RH_OFF;
  ushort* HPB = (ushort*)(ws + HPB_FOFF);
  int ncol0 = ntile * 64;
  int rg = tid >> 4, cg = tid & 15;
  int col0 = cg * 4;
  float acc[4][4] = {{0.f}};
  for (int kc = 0; kc < 8; ++kc) {
    int coff = (kc & 3) * 32;
    __syncthreads();
    #pragma unroll
    for (int t = 0; t < 2; ++t) {
      int idx = tid + t*256;
      int r = idx >> 3, q = idx & 7;
      float4 v;
      if (kc < 4) {
        float4 v0 = *(const float4*)&conv0[(size_t)(mbase + r)*HDIM + coff + q*4];
        float4 v1 = *(const float4*)&conv1[(size_t)(mbase + r)*HDIM + coff + q*4];
        float4 bv = *(const float4*)&bias_gat[coff + q*4];
        v.x = v0.x+v1.x+bv.x; v.y = v0.y+v1.y+bv.y;
        v.z = v0.z+v1.z+bv.z; v.w = v0.w+v1.w+bv.w;
      } else {
        v = *(const float4*)&rh[(size_t)(mbase + r)*HDIM + coff + q*4];
      }
      *(float4*)&a_l[r][q*4] = v;
    }
    #pragma unroll
    for (int t = 0; t < 2; ++t) {
      int idx = tid + t*256;
      int r = idx >> 4, q = idx & 15;
      *(float4*)&w_l[r][q*4] =
        *(const float4*)&W_c[(size_t)(kc*32 + r)*HDIM + ncol0 + q*4];
    }
    __syncthreads();
    for (int k = 0; k < 32; ++k) {
      float4 wv = *(const float4*)&w_l[k][col0];
      #pragma unroll
      for (int rr = 0; rr < 4; ++rr) {
        float av = a_l[rg*4+rr][k];
        acc[rr][0] = fmaf(av, wv.x, acc[rr][0]);
        acc[rr][1] = fmaf(av, wv.y, acc[rr][1]);
        acc[rr][2] = fmaf(av, wv.z, acc[rr][2]);
        acc[rr][3] = fmaf(av, wv.w, acc[rr][3]);
      }
    }
  }
  #pragma unroll
  for (int rr = 0; rr < 4; ++rr) {
    int m = mbase + rg*4 + rr;
    int n = m & (NNODES-1);
    float bv = b_c[n];
    float4 uv = *(const float4*)&out[U_OFF + (size_t)m*HDIM + ncol0 + col0];
    float4 hv = *(const float4*)&h_in[(size_t)m*HDIM + ncol0 + col0];
    float4 o;
    o.x = uv.x*hv.x + (1.0f-uv.x)*tanhf_(bv + acc[rr][0]);
    o.y = uv.y*hv.y + (1.0f-uv.y)*tanhf_(bv + acc[rr][1]);
    o.z = uv.z*hv.z + (1.0f-uv.z)*tanhf_(bv + acc[rr][2]);
    o.w = uv.w*hv.w + (1.0f-uv.w)*tanhf_(bv + acc[rr][3]);
    *(float4*)&out[HP_OFF + (size_t)m*HDIM + ncol0 + col0] = o;
    ushort4 ob;
    ob.x = f2b(o.x); ob.y = f2b(o.y); ob.z = f2b(o.z); ob.w = f2b(o.w);
    *(ushort4*)&HPB[(size_t)m*HDIM + ncol0 + col0] = ob;
  }
}

// ---------------- Kernel E: T[b][k3] = h' @ R_k3 (f32 compute, bf16 store) ---
#define HP_S 132
__global__ __launch_bounds__(128) void k_T(
    const float* __restrict__ R_p, const float* __restrict__ R_mu, const float* __restrict__ R_sg,
    const float* __restrict__ out, float* __restrict__ ws)
{
  __shared__ float hp_l[32*HP_S];
  int tid = threadIdx.x;
  int blk = blockIdx.x;
  int b = blk & 7;                 // XCD-local batch
  int rem = blk >> 3;              // 0..95
  int k3 = rem >> 5;
  int n0 = (rem & 31) * 32;
  const float* hp = out + HP_OFF;
  const float* R = (k3 == 0) ? R_p : (k3 == 1) ? R_mu : R_sg;
  #pragma unroll
  for (int t = 0; t < 8; ++t) {
    int idx = tid + t*128;
    int r = idx >> 5, c4 = idx & 31;
    *(float4*)&hp_l[r*HP_S + c4*4] =
      *(const float4*)&hp[((size_t)(b*NNODES)+n0+r)*HDIM + c4*4];
  }
  __syncthreads();
  int cg = tid & 31, rg = tid >> 5;
  float acc[8][4];
  #pragma unroll
  for (int rr = 0; rr < 8; ++rr)
    #pragma unroll
    for (int c = 0; c < 4; ++c) acc[rr][c] = 0.f;
  for (int k4 = 0; k4 < 32; ++k4) {
    float w[4][4];
    #pragma unroll
    for (int kk = 0; kk < 4; ++kk) ld4(&R[(size_t)(k4*4+kk)*HDIM + cg*4], w[kk]);
    #pragma unroll
    for (int rr = 0; rr < 8; ++rr) {
      float hv[4];
      ld4(&hp_l[(rg + 4*rr)*HP_S + k4*4], hv);
      #pragma unroll
      for (int c = 0; c < 4; ++c) {
        float s = acc[rr][c];
        s = fmaf(hv[0], w[0][c], s);
        s = fmaf(hv[1], w[1][c], s);
        s = fmaf(hv[2], w[2][c], s);
        s = fmaf(hv[3], w[3][c], s);
        acc[rr][c] = s;
      }
    }
  }
  ushort* TB = (ushort*)(ws + WS_T);
  #pragma unroll
  for (int rr = 0; rr < 8; ++rr) {
    int row = rg + 4*rr;
    ushort4 o;
    o.x = f2b(acc[rr][0]); o.y = f2b(acc[rr][1]);
    o.z = f2b(acc[rr][2]); o.w = f2b(acc[rr][3]);
    *(ushort4*)&TB[((size_t)((b*3+k3)*NNODES)+n0+row)*HDIM + cg*4] = o;
  }
}

// ---------------- Kernel F: logits via bf16 MFMA, 3 decoders fused ----------
#define LT_S 136   // bf16 row stride (272B): 2-way bank aliasing only
__global__ __launch_bounds__(256) void k_logits_m(
    const float* __restrict__ ws, float* __restrict__ out)
{
  __shared__ ushort t_b[3][64*LT_S];   // 52224 B
  __shared__ ushort hp_b[64*LT_S];     // 17408 B
  const ushort* TB  = (const ushort*)(ws + WS_T);
  const ushort* HPB = (const ushort*)(ws + HPB_FOFF);
  int tid = threadIdx.x;
  int blk = blockIdx.x;
  int b = blk & 7;                  // XCD-local batch
  int rem = blk >> 3;               // 0..255
  int nt = rem >> 4, mt = rem & 15;
  int n0 = nt*64, m0 = mt*64;
  #pragma unroll
  for (int t = 0; t < 4; ++t) {
    int idx = tid + t*256;
    int r = idx >> 4, c = idx & 15;
    *(uint4*)&hp_b[r*LT_S + c*8] =
      *(const uint4*)&HPB[((size_t)(b*NNODES)+m0+r)*HDIM + c*8];
  }
  #pragma unroll
  for (int t = 0; t < 12; ++t) {
    int idx = tid + t*256;
    int k3 = idx >> 10, r = (idx >> 4) & 63, c = idx & 15;
    *(uint4*)&t_b[k3][r*LT_S + c*8] =
      *(const uint4*)&TB[((size_t)((b*3+k3)*NNODES)+n0+r)*HDIM + c*8];
  }
  __syncthreads();
  int w = tid >> 6, lane = tid & 63;
  int nbase = (w >> 1) * 32, mbase = (w & 1) * 32;
  int frow = lane & 15, fk = (lane >> 4) * 8;
  f32x4 acc[3][2][2];
  #pragma unroll
  for (int k3 = 0; k3 < 3; ++k3)
    #pragma unroll
    for (int nn = 0; nn < 2; ++nn)
      #pragma unroll
      for (int mm = 0; mm < 2; ++mm) acc[k3][nn][mm] = (f32x4)0.f;
  #pragma unroll
  for (int ks = 0; ks < 4; ++ks) {
    int ko = ks*32 + fk;
    bf16x8 bfr[2];
    #pragma unroll
    for (int mm = 0; mm < 2; ++mm)
      bfr[mm] = *(const bf16x8*)&hp_b[(mbase + mm*16 + frow)*LT_S + ko];
    #pragma unroll
    for (int k3 = 0; k3 < 3; ++k3)
      #pragma unroll
      for (int nn = 0; nn < 2; ++nn) {
        bf16x8 afr = *(const bf16x8*)&t_b[k3][(nbase + nn*16 + frow)*LT_S + ko];
        #pragma unroll
        for (int mm = 0; mm < 2; ++mm)
          acc[k3][nn][mm] = __builtin_amdgcn_mfma_f32_16x16x32_bf16(
              afr, bfr[mm], acc[k3][nn][mm], 0, 0, 0);
      }
  }
  int crow = (lane >> 4) * 4, ccol = lane & 15;
  #pragma unroll
  for (int nn = 0; nn < 2; ++nn)
    #pragma unroll
    for (int mm = 0; mm < 2; ++mm)
      #pragma unroll
      for (int r = 0; r < 4; ++r) {
        int n = n0 + nbase + nn*16 + crow + r;
        int m = m0 + mbase + mm*16 + ccol;
        float* po = &out[(((size_t)(b*NNODES) + n)*NNODES + m)*3];
        po[0] = acc[0][nn][mm][r];
        po[1] = acc[1][nn][mm][r];
        po[2] = acc[2][nn][mm][r];
      }
}

extern "C" void kernel_launch(void* const* d_in, const int* in_sizes, int n_in,
                              void* d_out, int out_size, void* d_ws, size_t ws_size,
                              hipStream_t stream) {
  (void)in_sizes; (void)n_in; (void)out_size; (void)ws_size;
  const float* x        = (const float*)d_in[0];
  const float* a        = (const float*)d_in[1];
  const float* h        = (const float*)d_in[2];
  const float* Wk       = (const float*)d_in[3];
  const float* att_src  = (const float*)d_in[4];
  const float* att_dst  = (const float*)d_in[5];
  const float* bias_gat = (const float*)d_in[6];
  const float* b_u      = (const float*)d_in[7];
  const float* b_r      = (const float*)d_in[8];
  const float* b_c      = (const float*)d_in[9];
  const float* W_u      = (const float*)d_in[10];
  const float* W_r      = (const float*)d_in[11];
  const float* W_c      = (const float*)d_in[12];
  const float* R_p      = (const float*)d_in[13];
  const float* R_mu     = (const float*)d_in[14];
  const float* R_sg     = (const float*)d_in[15];
  float* out = (float*)d_out;
  float* ws  = (float*)d_ws;

  hipLaunchKernelGGL(k_hh_scores, dim3(1024), dim3(256), 0, stream,
                     x, Wk, att_src, att_dst, ws, out);
  hipLaunchKernelGGL(k_stats, dim3(8192), dim3(256), 0, stream, a, ws);
  hipLaunchKernelGGL(k_conv_m, dim3(256), dim3(256), 0, stream, a, ws, out);
  hipLaunchKernelGGL(k_gruA, dim3(512), dim3(256), 0, stream,
                     h, b_u, b_r, W_u, W_r, bias_gat, ws, out);
  hipLaunchKernelGGL(k_gruB, dim3(256), dim3(256), 0, stream,
                     h, b_c, W_c, bias_gat, ws, out);
  hipLaunchKernelGGL(k_T, dim3(768), dim3(128), 0, stream, R_p, R_mu, R_sg, out, ws);
  hipLaunchKernelGGL(k_logits_m, dim3(2048), dim3(256), 0, stream, ws, out);
}